// Round 5
// baseline (505.265 us; speedup 1.0000x reference)
//
#include <hip/hip_runtime.h>
#include <hip/hip_bf16.h>

#define B_IMG 8192
#define FC_ROWS 4
#define FC_NBLK (B_IMG / FC_ROWS)   // 2048

// ---- ws layout (bytes) ----
#define OFF_SD    64                       // 1 float (RBF sum of squares)
#define OFF_PROJ  128                      // 8192*4 doubles = 262144
#define OFF_PN64  (128 + 262144)           // 8192*4 doubles
#define OFF_PB32  (OFF_PN64 + 262144)      // 8192*4 floats
#define OFF_PN32  (OFF_PB32 + 131072)
#define OFF_WP32  (OFF_PN32 + 131072)
#define OFF_W1T   (OFF_WP32 + 131072)      // 784*64 floats = 200704
#define OFF_PSUM  (OFF_W1T + 200704)       // 2048*8 doubles = 131072
#define OFF_FLAT  1310720                  // flat: f64 (51.4MB) or f32 fallback
#define FLAT64_BYTES (8192UL * 784UL * 8UL)

// ---------------------------------------------------------------------------
// Kernel 0: setup — zero sd; transpose fc1w -> w1t[k][o] (f32). 64 blocks.
// ---------------------------------------------------------------------------
__global__ __launch_bounds__(256) void setup_kernel(
    const float* __restrict__ fc1w, float* __restrict__ w1t,
    float* __restrict__ sd) {
    const int t = threadIdx.x;
    if (blockIdx.x == 0 && t == 0) sd[0] = 0.f;
    for (int i = blockIdx.x * 256 + t; i < 784 * 64; i += 64 * 256) {
        const int o = i & 63, k = i >> 6;
        w1t[i] = fc1w[o * 784 + k];     // w1t[k*64+o]
    }
}

// ---------------------------------------------------------------------------
// Kernel 1: fused conv1+relu+pool -> conv2+relu+pool, all f64 compute.
// One image per 256-thread block. conv2 weights gathered per-lane from w2
// (L2-hot, registers). h1s pad 9 -> uniform 2-way LDS (free). conv2 results
// stored directly to flat (no h2s buffer). Arithmetic order identical to r4.
// ---------------------------------------------------------------------------
#define H1PAD 9
template <bool F64OUT>
__global__ __launch_bounds__(256) void conv_fused(
    const float* __restrict__ x,
    const float* __restrict__ w1, const float* __restrict__ b1,
    const float* __restrict__ w2, const float* __restrict__ b2,
    void* __restrict__ flatv) {

    __shared__ __align__(16) double xs[900];              // padded 30x30 f64
    __shared__ __align__(16) double h1s[16 * 16 * H1PAD]; // padded 14x14 [y][x][ic]

    const int b = blockIdx.x;
    const int t = threadIdx.x;
    const float* xb = x + (size_t)b * 784;

    // stage-2 lane mapping; gather weights early (f32 -> f64 exact)
    const int c2 = t >> 4;          // 0..15 out-channel
    const int icp = (t >> 3) & 1;   // ic half
    const int g2 = t & 7;           // q group
    double wgt[9][4];
#pragma unroll
    for (int m = 0; m < 4; ++m) {
        const float* wsrc = w2 + c2 * 72 + (icp * 4 + m) * 9;
#pragma unroll
        for (int j = 0; j < 9; ++j) wgt[j][m] = (double)wsrc[j];
    }
    const double bias2 = (double)b2[c2];

    // phase A: zero padded buffers
    for (int i = t; i < 900; i += 256) xs[i] = 0.0;
    for (int i = t; i < 16 * 16 * H1PAD; i += 256) h1s[i] = 0.0;
    __syncthreads();
    // phase B: fill xs interior (f32 -> f64 exact)
    for (int i = t; i < 784; i += 256) {
        const int yy = i / 28, xx = i - yy * 28;
        xs[(yy + 1) * 30 + (xx + 1)] = (double)xb[i];
    }
    __syncthreads();

    // ---- stage 1: conv1 + relu + maxpool (f64) -> h1s interior
    {
        const int c1 = t & 7;
        double wc[9];
#pragma unroll
        for (int j = 0; j < 9; ++j) wc[j] = (double)w1[c1 * 9 + j];
        const double bb = (double)b1[c1];
        for (int q = (t >> 3); q < 196; q += 32) {
            const int py = q / 14, px = q - py * 14;
            double r2[4][4];
#pragma unroll
            for (int rr = 0; rr < 4; ++rr)
#pragma unroll
                for (int cc = 0; cc < 4; ++cc)
                    r2[rr][cc] = xs[(2 * py + rr) * 30 + 2 * px + cc];
            double s[2][2] = {{bb, bb}, {bb, bb}};
#pragma unroll
            for (int dy = 0; dy < 2; ++dy)
#pragma unroll
                for (int dx = 0; dx < 2; ++dx)
#pragma unroll
                    for (int ky = 0; ky < 3; ++ky)
#pragma unroll
                        for (int kx = 0; kx < 3; ++kx)
                            s[dy][dx] = fma(r2[dy + ky][dx + kx], wc[ky * 3 + kx], s[dy][dx]);
            double mx = fmax(fmax(s[0][0], s[0][1]), fmax(s[1][0], s[1][1]));
            mx = fmax(mx, 0.0);   // pool(relu) == relu(maxpool), exactly
            h1s[((py + 1) * 16 + (px + 1)) * H1PAD + c1] = mx;
        }
    }
    __syncthreads();

    // ---- stage 2: conv2 + relu + maxpool (f64), weights in regs,
    // direct global writeout (no h2s). Same accumulation order as r4.
    for (int q = g2; q < 49; q += 8) {
        const int py = q / 7, px = q - py * 7;
        double s00 = 0, s01 = 0, s10 = 0, s11 = 0;
#pragma unroll
        for (int rr = 0; rr < 4; ++rr)
#pragma unroll
            for (int cc = 0; cc < 4; ++cc) {
                const double* hp = &h1s[((2 * py + rr) * 16 + 2 * px + cc) * H1PAD + icp * 4];
                const double v0 = hp[0], v1 = hp[1], v2 = hp[2], v3 = hp[3];
#pragma unroll
                for (int dy = 0; dy < 2; ++dy) {
                    const int ky = rr - dy;
                    if (ky < 0 || ky > 2) continue;   // constant-folds
#pragma unroll
                    for (int dx = 0; dx < 2; ++dx) {
                        const int kx = cc - dx;
                        if (kx < 0 || kx > 2) continue;
                        const int tap = ky * 3 + kx;
                        double acc = (dy == 0) ? (dx == 0 ? s00 : s01)
                                               : (dx == 0 ? s10 : s11);
                        acc = fma(v0, wgt[tap][0], acc);
                        acc = fma(v1, wgt[tap][1], acc);
                        acc = fma(v2, wgt[tap][2], acc);
                        acc = fma(v3, wgt[tap][3], acc);
                        if (dy == 0) { if (dx == 0) s00 = acc; else s01 = acc; }
                        else         { if (dx == 0) s10 = acc; else s11 = acc; }
                    }
                }
            }
        // combine ic halves (partner lane t^8, same wave)
        s00 += __shfl_xor(s00, 8);
        s01 += __shfl_xor(s01, 8);
        s10 += __shfl_xor(s10, 8);
        s11 += __shfl_xor(s11, 8);
        if (icp == 0) {
            double mx = fmax(fmax(s00, s01), fmax(s10, s11));
            mx = fmax(bias2 + mx, 0.0);
            if (F64OUT) ((double*)flatv)[(size_t)b * 784 + c2 * 49 + q] = mx;
            else        ((float*)flatv)[(size_t)b * 784 + c2 * 49 + q] = (float)mx;
        }
    }
}

// ---------------------------------------------------------------------------
// Kernel 2: streaming FC1 (784->64, relu) + FC2 (64->4) + BN stat partials.
// 2048 blocks x 256 thr; 4 rows staged in LDS (f64); weights via w1t
// (coalesced). Per-block partials to psum (no atomics).
// ---------------------------------------------------------------------------
template <bool F64IN>
__global__ __launch_bounds__(256) void fc_kernel(
    const void* __restrict__ flatv, const float* __restrict__ w1t,
    const float* __restrict__ fc1b,
    const float* __restrict__ fc2w, const float* __restrict__ fc2b,
    double* __restrict__ proj, double* __restrict__ psum) {

    __shared__ __align__(16) double rows[FC_ROWS][784];
    __shared__ __align__(16) double Hs[FC_ROWS][64];
    __shared__ double w2t[256];   // [o][kc] fc2 transposed

    const int t = threadIdx.x;
    const int row0 = blockIdx.x * FC_ROWS;

    w2t[t] = (double)fc2w[(t & 3) * 64 + (t >> 2)];
    for (int i = t; i < FC_ROWS * 784; i += 256) {
        const int r = i / 784, k = i - r * 784;
        double v;
        if (F64IN) v = ((const double*)flatv)[(size_t)(row0 + r) * 784 + k];
        else       v = (double)((const float*)flatv)[(size_t)(row0 + r) * 784 + k];
        rows[r][k] = v;
    }
    __syncthreads();

    const int o = t & 63, s = t >> 6;
    const double* rp = rows[s];
    double acc0 = 0.0, acc1 = 0.0;
    for (int k = 0; k < 784; k += 4) {
        double2 x01 = *(const double2*)&rp[k];
        double2 x23 = *(const double2*)&rp[k + 2];
        const float wa = w1t[(k + 0) * 64 + o];
        const float wb = w1t[(k + 1) * 64 + o];
        const float wc = w1t[(k + 2) * 64 + o];
        const float wd = w1t[(k + 3) * 64 + o];
        acc0 = fma(x01.x, (double)wa, acc0);
        acc1 = fma(x01.y, (double)wb, acc1);
        acc0 = fma(x23.x, (double)wc, acc0);
        acc1 = fma(x23.y, (double)wd, acc1);
    }
    Hs[s][o] = fmax((acc0 + acc1) + (double)fc1b[o], 0.0);
    __syncthreads();

    if (t < 16) {
        const int r = t >> 2, kc = t & 3;
        double sv = (double)fc2b[kc];
#pragma unroll 8
        for (int c = 0; c < 64; ++c) sv = fma(Hs[r][c], w2t[c * 4 + kc], sv);
        proj[(size_t)(row0 + r) * 4 + kc] = sv;
        double ssum = sv, sq = sv * sv;
        ssum += __shfl_xor(ssum, 4);  sq += __shfl_xor(sq, 4);
        ssum += __shfl_xor(ssum, 8);  sq += __shfl_xor(sq, 8);
        if (t < 4) {
            psum[(size_t)blockIdx.x * 8 + t] = ssum;
            psum[(size_t)blockIdx.x * 8 + 4 + t] = sq;
        }
    }
}

// ---------------------------------------------------------------------------
// Kernel 3: stats-reduce (replicated per block, bit-identical order) +
// BatchNorm + row L2-normalize, f64. Emits pb32/pn32 + pn64.
// ---------------------------------------------------------------------------
__global__ __launch_bounds__(256) void bn_kernel(
    const double* __restrict__ proj, const double* __restrict__ psum,
    const float* __restrict__ gamma, const float* __restrict__ beta,
    float* __restrict__ pb32, float* __restrict__ pn32,
    double* __restrict__ pn64) {

    __shared__ double red[256];
    __shared__ double stats_s[8];
    const int t = threadIdx.x;
    {   // identical reduction order to r4's reduce_stats
        const int c = t & 7, i0 = t >> 3;
        double v = 0.0;
        for (int i = i0; i < FC_NBLK; i += 32) v += psum[(size_t)i * 8 + c];
        red[t] = v;
    }
    __syncthreads();
    if (t < 8) {
        double sacc = 0.0;
        for (int j = 0; j < 32; ++j) sacc += red[t + 8 * j];
        stats_s[t] = sacc;
    }
    __syncthreads();

    const int i = blockIdx.x * 256 + t;
    double2 p01 = ((const double2*)proj)[2 * i];
    double2 p23 = ((const double2*)proj)[2 * i + 1];
    double pv[4] = {p01.x, p01.y, p23.x, p23.y};
    double o[4];
#pragma unroll
    for (int k = 0; k < 4; ++k) {
        double mean = stats_s[k] * (1.0 / 8192.0);
        double var  = stats_s[4 + k] * (1.0 / 8192.0) - mean * mean;
        double inv  = 1.0 / sqrt(var + 1e-5);
        o[k] = (pv[k] - mean) * inv * (double)gamma[k] + (double)beta[k];
    }
    double nrm = sqrt(o[0] * o[0] + o[1] * o[1] + o[2] * o[2] + o[3] * o[3]);
    double innv = 1.0 / (nrm + 1e-12);
    ((float4*)pb32)[i] = make_float4((float)o[0], (float)o[1], (float)o[2], (float)o[3]);
    double n0 = o[0] * innv, n1 = o[1] * innv, n2 = o[2] * innv, n3 = o[3] * innv;
    ((float4*)pn32)[i] = make_float4((float)n0, (float)n1, (float)n2, (float)n3);
    double2* pd = (double2*)(pn64 + (size_t)i * 4);
    pd[0] = make_double2(n0, n1);
    pd[1] = make_double2(n2, n3);
}

// ---------------------------------------------------------------------------
// Kernel 4: O(B^2) adjacency. fp32 fast path, +-2e-4 guard band with f64
// recheck. 32 rows/block (2 rows/lane x 16 j-lanes) -> 256 blocks (all CUs).
// ---------------------------------------------------------------------------
#define CHUNK 1024
__global__ __launch_bounds__(256) void adj_kernel(
    const float* __restrict__ pn32, const float* __restrict__ pb32,
    const double* __restrict__ pn64,
    float* __restrict__ wp32, float* __restrict__ sd) {

    __shared__ __align__(16) float4 pns[CHUNK];
    __shared__ __align__(16) float4 pbs[CHUNK];
    __shared__ float bpart[16];

    const int t = threadIdx.x;
    const int tg = t & 15, g = t >> 4;
    const int rowb = blockIdx.x * 32 + g * 2;

    float4 pni[2];
#pragma unroll
    for (int r = 0; r < 2; ++r) pni[r] = ((const float4*)pn32)[rowb + r];
    float w[2][4] = {};

    for (int base = 0; base < 8192; base += CHUNK) {
        __syncthreads();
        for (int i = t; i < CHUNK; i += 256) {
            pns[i] = ((const float4*)pn32)[base + i];
            pbs[i] = ((const float4*)pb32)[base + i];
        }
        __syncthreads();
        for (int jj = 0; jj < CHUNK / 16; ++jj) {
            const int jl = jj * 16 + tg;
            const int j = base + jl;
            float4 q = pns[jl];
            float4 pj = pbs[jl];
#pragma unroll
            for (int r = 0; r < 2; ++r) {
                float d = fmaf(pni[r].x, q.x, fmaf(pni[r].y, q.y,
                          fmaf(pni[r].z, q.z, pni[r].w * q.w)));
                float fid = d * d;
                bool ok;
                if (fabsf(fid - 0.9f) < 2e-4f) {   // rare: exact recheck
                    const double2* pr = (const double2*)(pn64 + (size_t)(rowb + r) * 4);
                    const double2* pq = (const double2*)(pn64 + (size_t)j * 4);
                    double2 r0 = pr[0], r1 = pr[1], q0 = pq[0], q1 = pq[1];
                    double dd = fma(r0.x, q0.x, fma(r0.y, q0.y,
                                fma(r1.x, q1.x, r1.y * q1.y)));
                    ok = (dd * dd >= 0.9);
                } else {
                    ok = (fid >= 0.9f);
                }
                float m = (ok && j != (rowb + r)) ? 1.f : 0.f;
                w[r][0] = fmaf(m, pj.x, w[r][0]);
                w[r][1] = fmaf(m, pj.y, w[r][1]);
                w[r][2] = fmaf(m, pj.z, w[r][2]);
                w[r][3] = fmaf(m, pj.w, w[r][3]);
            }
        }
    }
#pragma unroll
    for (int m = 1; m < 16; m <<= 1)
#pragma unroll
        for (int r = 0; r < 2; ++r) {
            w[r][0] += __shfl_xor(w[r][0], m);
            w[r][1] += __shfl_xor(w[r][1], m);
            w[r][2] += __shfl_xor(w[r][2], m);
            w[r][3] += __shfl_xor(w[r][3], m);
        }
    if (tg == 0) {
        float ds_ = 0.f;
#pragma unroll
        for (int r = 0; r < 2; ++r) {
            ((float4*)wp32)[rowb + r] = make_float4(w[r][0], w[r][1], w[r][2], w[r][3]);
            float4 pbv = ((const float4*)pb32)[rowb + r];
            float d0 = pbv.x - w[r][0], d1 = pbv.y - w[r][1];
            float d2 = pbv.z - w[r][2], d3 = pbv.w - w[r][3];
            ds_ += d0 * d0 + d1 * d1 + d2 * d2 + d3 * d3;
        }
        bpart[g] = ds_;
    }
    __syncthreads();
    if (t == 0) {
        float sacc = 0.f;
#pragma unroll
        for (int i = 0; i < 16; ++i) sacc += bpart[i];
        atomicAdd(sd, sacc);
    }
}

// ---------------------------------------------------------------------------
// Kernel 5: epilogue -> probs
// ---------------------------------------------------------------------------
__global__ __launch_bounds__(256) void final_kernel(
    const float* __restrict__ pb32, const float* __restrict__ wp32,
    const float* __restrict__ sd, float* __restrict__ out) {

    const int i = blockIdx.x * 256 + threadIdx.x;
    const double kv = exp(-(double)sd[0]);
    float4 p = ((const float4*)pb32)[i];
    float4 w = ((const float4*)wp32)[i];
    double logit = (double)p.x + p.y + p.z + p.w
                 + (double)w.x + w.y + w.z + w.w + kv;
    double pr = 1.0 / (1.0 + exp(-logit));
    *(float2*)&out[2 * i] = make_float2((float)pr, (float)(1.0 - pr));
}

// ---------------------------------------------------------------------------
extern "C" void kernel_launch(void* const* d_in, const int* in_sizes, int n_in,
                              void* d_out, int out_size, void* d_ws, size_t ws_size,
                              hipStream_t stream) {
    const float* x     = (const float*)d_in[0];
    const float* c1w   = (const float*)d_in[1];
    const float* c1b   = (const float*)d_in[2];
    const float* c2w   = (const float*)d_in[3];
    const float* c2b   = (const float*)d_in[4];
    const float* fc1w  = (const float*)d_in[5];
    const float* fc1b  = (const float*)d_in[6];
    const float* fc2w  = (const float*)d_in[7];
    const float* fc2b  = (const float*)d_in[8];
    const float* gamma = (const float*)d_in[9];
    const float* beta  = (const float*)d_in[10];
    float* out = (float*)d_out;

    char* ws = (char*)d_ws;
    float*  sd    = (float*)(ws + OFF_SD);
    double* proj  = (double*)(ws + OFF_PROJ);
    double* pn64  = (double*)(ws + OFF_PN64);
    float*  pb32  = (float*)(ws + OFF_PB32);
    float*  pn32  = (float*)(ws + OFF_PN32);
    float*  wp32  = (float*)(ws + OFF_WP32);
    float*  w1t   = (float*)(ws + OFF_W1T);
    double* psum  = (double*)(ws + OFF_PSUM);
    void*   flat  = (void*)(ws + OFF_FLAT);

    // deterministic per-deployment branch (ws_size constant across calls)
    const bool f64flat = ws_size >= (size_t)OFF_FLAT + FLAT64_BYTES;

    setup_kernel<<<64, 256, 0, stream>>>(fc1w, w1t, sd);
    if (f64flat) {
        conv_fused<true><<<B_IMG, 256, 0, stream>>>(x, c1w, c1b, c2w, c2b, flat);
        fc_kernel<true><<<FC_NBLK, 256, 0, stream>>>(flat, w1t, fc1b, fc2w, fc2b, proj, psum);
    } else {
        conv_fused<false><<<B_IMG, 256, 0, stream>>>(x, c1w, c1b, c2w, c2b, flat);
        fc_kernel<false><<<FC_NBLK, 256, 0, stream>>>(flat, w1t, fc1b, fc2w, fc2b, proj, psum);
    }
    bn_kernel<<<B_IMG / 256, 256, 0, stream>>>(proj, psum, gamma, beta, pb32, pn32, pn64);
    adj_kernel<<<B_IMG / 32, 256, 0, stream>>>(pn32, pb32, pn64, wp32, sd);
    final_kernel<<<B_IMG / 256, 256, 0, stream>>>(pb32, wp32, sd, out);
}

// Round 6
// 478.281 us; speedup vs baseline: 1.0564x; 1.0564x over previous
//
#include <hip/hip_runtime.h>
#include <hip/hip_bf16.h>

#define B_IMG 8192
#define FC_ROWS 4
#define FC_NBLK (B_IMG / FC_ROWS)   // 2048

// ---- ws layout (bytes) ----
#define OFF_SD    64                       // 1 float (RBF sum of squares)
#define OFF_PROJ  128                      // 8192*4 doubles = 262144
#define OFF_PN64  (128 + 262144)           // 8192*4 doubles
#define OFF_PB32  (OFF_PN64 + 262144)      // 8192*4 floats
#define OFF_PN32  (OFF_PB32 + 131072)
#define OFF_WP32  (OFF_PN32 + 131072)
#define OFF_W1T   (OFF_WP32 + 131072)      // 784*64 floats = 200704
#define OFF_PSUM  (OFF_W1T + 200704)       // 2048*8 doubles = 131072
#define OFF_FLAT  1310720                  // flat: f64 (51.4MB) or f32 fallback
#define FLAT64_BYTES (8192UL * 784UL * 8UL)

// h1 LDS geometry: 16 rows x 16 cells, cell = 8 doubles @ stride 10,
// row pitch 164 doubles  ->  per-read lane addresses hit bank-pair windows
// {0,4,8,12} mod 16 (icp:+4, row-pair:+8) => conflict-free ds_read_b128.
#define H1_CS   10
#define H1_RP   164

// ---------------------------------------------------------------------------
// Kernel 0: setup — zero sd; transpose fc1w -> w1t[k][o] (f32). 64 blocks.
// ---------------------------------------------------------------------------
__global__ __launch_bounds__(256) void setup_kernel(
    const float* __restrict__ fc1w, float* __restrict__ w1t,
    float* __restrict__ sd) {
    const int t = threadIdx.x;
    if (blockIdx.x == 0 && t == 0) sd[0] = 0.f;
    for (int i = blockIdx.x * 256 + t; i < 784 * 64; i += 64 * 256) {
        const int o = i & 63, k = i >> 6;
        w1t[i] = fc1w[o * 784 + k];     // w1t[k*64+o]
    }
}

// ---------------------------------------------------------------------------
// conv2 helpers: compile-time buffer index (rule: no runtime-indexed
// register arrays). W[buf][row][colslot][lo/hi] holds a 4x4-cell window.
// ---------------------------------------------------------------------------
template <int BUF>
__device__ __forceinline__ void ldpair(
    double2 (&W)[2][4][2][2], const double* __restrict__ h1s,
    int rowb, int c0, int icp) {
#pragma unroll
    for (int wr = 0; wr < 4; ++wr) {
#pragma unroll
        for (int cc = 0; cc < 2; ++cc) {
            const double* p = h1s + (rowb + wr) * H1_RP + (c0 + cc) * H1_CS + icp * 4;
            W[BUF][wr][cc][0] = *(const double2*)p;
            W[BUF][wr][cc][1] = *(const double2*)(p + 2);
        }
    }
}

template <int PHASE>
__device__ __forceinline__ void conv2_step(
    const double2 (&W)[2][4][2][2], const double (&wgt)[9][4],
    double bias2, int c2, int icp, int pys, int px,
    double* __restrict__ h2s) {
    double s00 = 0, s01 = 0, s10 = 0, s11 = 0;
#pragma unroll
    for (int dy = 0; dy < 2; ++dy)
#pragma unroll
        for (int dx = 0; dx < 2; ++dx)
#pragma unroll
            for (int ky = 0; ky < 3; ++ky)
#pragma unroll
                for (int kx = 0; kx < 3; ++kx) {
                    const int wr = dy + ky, wc = dx + kx;
                    const int buf = (wc < 2) ? PHASE : (1 - PHASE);
                    const int sl = wc & 1;
                    double2 lo = W[buf][wr][sl][0];
                    double2 hi = W[buf][wr][sl][1];
                    double a = (dy == 0) ? ((dx == 0) ? s00 : s01)
                                         : ((dx == 0) ? s10 : s11);
                    a = fma(lo.x, wgt[ky * 3 + kx][0], a);
                    a = fma(lo.y, wgt[ky * 3 + kx][1], a);
                    a = fma(hi.x, wgt[ky * 3 + kx][2], a);
                    a = fma(hi.y, wgt[ky * 3 + kx][3], a);
                    if (dy == 0) { if (dx == 0) s00 = a; else s01 = a; }
                    else         { if (dx == 0) s10 = a; else s11 = a; }
                }
    // combine ic halves (partner lane t^16, same wave, same pys)
    s00 += __shfl_xor(s00, 16);
    s01 += __shfl_xor(s01, 16);
    s10 += __shfl_xor(s10, 16);
    s11 += __shfl_xor(s11, 16);
    if (icp == 0) {
        double mx = fmax(fmax(s00, s01), fmax(s10, s11));
        h2s[c2 * 49 + pys * 7 + px] = fmax(bias2 + mx, 0.0);
    }
}

// ---------------------------------------------------------------------------
// Kernel 1: fused conv1+relu+pool -> conv2+relu+pool, all f64 compute.
// One image per 256-thread block. Stage 2: lane=(c2,icp,py-strip); 4x4-cell
// window ping-pongs between 2 register buffers (column reuse halves LDS
// reads); conflict-free h1 layout; h2s buffer + coalesced writeout.
// ---------------------------------------------------------------------------
template <bool F64OUT>
__global__ __launch_bounds__(256) void conv_fused(
    const float* __restrict__ x,
    const float* __restrict__ w1, const float* __restrict__ b1,
    const float* __restrict__ w2, const float* __restrict__ b2,
    void* __restrict__ flatv) {

    __shared__ __align__(16) float  xs[900];            // padded 30x30 f32
    __shared__ __align__(16) double h1s[16 * H1_RP];    // padded 14x14, strided
    __shared__ __align__(16) double h2s[784];           // [c][7][7]

    const int b = blockIdx.x;
    const int t = threadIdx.x;
    const float* xb = x + (size_t)b * 784;

    // stage-2 lane mapping; gather weights early (f32 -> f64 exact, L1-hot)
    const int c2 = t & 15, icp = (t >> 4) & 1, pys = t >> 5;   // pys 0..7
    double wgt[9][4];
#pragma unroll
    for (int m = 0; m < 4; ++m) {
        const float* wsrc = w2 + c2 * 72 + (icp * 4 + m) * 9;
#pragma unroll
        for (int j = 0; j < 9; ++j) wgt[j][m] = (double)wsrc[j];
    }
    const double bias2 = (double)b2[c2];

    // phase A: zero padded buffers
    for (int i = t; i < 900; i += 256) xs[i] = 0.f;
    for (int i = t; i < 16 * H1_RP; i += 256) h1s[i] = 0.0;
    __syncthreads();
    // phase B: fill xs interior
    for (int i = t; i < 784; i += 256) {
        const int yy = i / 28, xx = i - yy * 28;
        xs[(yy + 1) * 30 + (xx + 1)] = xb[i];
    }
    __syncthreads();

    // ---- stage 1: conv1 + relu + maxpool (f64) -> h1s interior
    {
        const int c1 = t & 7;
        double wc[9];
#pragma unroll
        for (int j = 0; j < 9; ++j) wc[j] = (double)w1[c1 * 9 + j];
        const double bb = (double)b1[c1];
        for (int q = (t >> 3); q < 196; q += 32) {
            const int py = q / 14, px = q - py * 14;
            double r2[4][4];
#pragma unroll
            for (int rr = 0; rr < 4; ++rr)
#pragma unroll
                for (int cc = 0; cc < 4; ++cc)
                    r2[rr][cc] = (double)xs[(2 * py + rr) * 30 + 2 * px + cc];
            double s[2][2] = {{bb, bb}, {bb, bb}};
#pragma unroll
            for (int dy = 0; dy < 2; ++dy)
#pragma unroll
                for (int dx = 0; dx < 2; ++dx)
#pragma unroll
                    for (int ky = 0; ky < 3; ++ky)
#pragma unroll
                        for (int kx = 0; kx < 3; ++kx)
                            s[dy][dx] = fma(r2[dy + ky][dx + kx], wc[ky * 3 + kx], s[dy][dx]);
            double mx = fmax(fmax(s[0][0], s[0][1]), fmax(s[1][0], s[1][1]));
            mx = fmax(mx, 0.0);   // pool(relu) == relu(maxpool), exactly
            h1s[(py + 1) * H1_RP + (px + 1) * H1_CS + c1] = mx;
        }
    }
    __syncthreads();

    // ---- stage 2: conv2 + relu + maxpool (f64), strip per lane
    if (pys < 7) {
        const int rowb = 2 * pys;     // h1 rows rowb..rowb+3
        double2 W[2][4][2][2];
        ldpair<0>(W, h1s, rowb, 0, icp);
        ldpair<1>(W, h1s, rowb, 2, icp);
#pragma unroll
        for (int px = 0; px < 7; ++px) {
            if ((px & 1) == 0) {
                conv2_step<0>(W, wgt, bias2, c2, icp, pys, px, h2s);
                if (px < 6) ldpair<0>(W, h1s, rowb, 2 * px + 4, icp);
            } else {
                conv2_step<1>(W, wgt, bias2, c2, icp, pys, px, h2s);
                if (px < 6) ldpair<1>(W, h1s, rowb, 2 * px + 4, icp);
            }
        }
    }
    __syncthreads();

    // coalesced writeout of the flat row
    if (F64OUT) {
        double2* dst = (double2*)((double*)flatv + (size_t)b * 784);
        const double2* src = (const double2*)h2s;
        for (int i = t; i < 392; i += 256) dst[i] = src[i];
    } else {
        float* dst = (float*)flatv + (size_t)b * 784;
        for (int i = t; i < 784; i += 256) dst[i] = (float)h2s[i];
    }
}

// ---------------------------------------------------------------------------
// Kernel 2: streaming FC1 (784->64, relu) + FC2 (64->4) + BN stat partials.
// 2048 blocks x 256 thr. Row data read DIRECTLY from global, wave-uniform
// (one L2 transaction, broadcast) — no LDS row staging. Weights coalesced
// via w1t. Per-block partials to psum (no atomics). Same f64 math order.
// ---------------------------------------------------------------------------
template <bool F64IN>
__global__ __launch_bounds__(256) void fc_kernel(
    const void* __restrict__ flatv, const float* __restrict__ w1t,
    const float* __restrict__ fc1b,
    const float* __restrict__ fc2w, const float* __restrict__ fc2b,
    double* __restrict__ proj, double* __restrict__ psum) {

    __shared__ __align__(16) double Hs[FC_ROWS][64];
    __shared__ double w2t[256];   // [o][kc] fc2 transposed

    const int t = threadIdx.x;
    const int row0 = blockIdx.x * FC_ROWS;

    w2t[t] = (double)fc2w[(t & 3) * 64 + (t >> 2)];

    const int o = t & 63, s = t >> 6;
    double acc0 = 0.0, acc1 = 0.0;
#pragma unroll 4
    for (int k = 0; k < 784; k += 4) {
        double x0, x1, x2, x3;
        if (F64IN) {
            const double* rp = (const double*)flatv + (size_t)(row0 + s) * 784;
            double2 a = *(const double2*)&rp[k];
            double2 c = *(const double2*)&rp[k + 2];
            x0 = a.x; x1 = a.y; x2 = c.x; x3 = c.y;
        } else {
            const float* rp = (const float*)flatv + (size_t)(row0 + s) * 784;
            float4 f = *(const float4*)&rp[k];
            x0 = (double)f.x; x1 = (double)f.y; x2 = (double)f.z; x3 = (double)f.w;
        }
        const float wa = w1t[(k + 0) * 64 + o];
        const float wb = w1t[(k + 1) * 64 + o];
        const float wc = w1t[(k + 2) * 64 + o];
        const float wd = w1t[(k + 3) * 64 + o];
        acc0 = fma(x0, (double)wa, acc0);
        acc1 = fma(x1, (double)wb, acc1);
        acc0 = fma(x2, (double)wc, acc0);
        acc1 = fma(x3, (double)wd, acc1);
    }
    Hs[s][o] = fmax((acc0 + acc1) + (double)fc1b[o], 0.0);
    __syncthreads();

    if (t < 16) {
        const int r = t >> 2, kc = t & 3;
        double sv = (double)fc2b[kc];
#pragma unroll 8
        for (int c = 0; c < 64; ++c) sv = fma(Hs[r][c], w2t[c * 4 + kc], sv);
        proj[(size_t)(row0 + r) * 4 + kc] = sv;
        double ssum = sv, sq = sv * sv;
        ssum += __shfl_xor(ssum, 4);  sq += __shfl_xor(sq, 4);
        ssum += __shfl_xor(ssum, 8);  sq += __shfl_xor(sq, 8);
        if (t < 4) {
            psum[(size_t)blockIdx.x * 8 + t] = ssum;
            psum[(size_t)blockIdx.x * 8 + 4 + t] = sq;
        }
    }
}

// ---------------------------------------------------------------------------
// Kernel 3: stats-reduce (replicated per block, bit-identical order) +
// BatchNorm + row L2-normalize, f64. Emits pb32/pn32 + pn64.
// ---------------------------------------------------------------------------
__global__ __launch_bounds__(256) void bn_kernel(
    const double* __restrict__ proj, const double* __restrict__ psum,
    const float* __restrict__ gamma, const float* __restrict__ beta,
    float* __restrict__ pb32, float* __restrict__ pn32,
    double* __restrict__ pn64) {

    __shared__ double red[256];
    __shared__ double stats_s[8];
    const int t = threadIdx.x;
    {
        const int c = t & 7, i0 = t >> 3;
        double v = 0.0;
        for (int i = i0; i < FC_NBLK; i += 32) v += psum[(size_t)i * 8 + c];
        red[t] = v;
    }
    __syncthreads();
    if (t < 8) {
        double sacc = 0.0;
        for (int j = 0; j < 32; ++j) sacc += red[t + 8 * j];
        stats_s[t] = sacc;
    }
    __syncthreads();

    const int i = blockIdx.x * 256 + t;
    double2 p01 = ((const double2*)proj)[2 * i];
    double2 p23 = ((const double2*)proj)[2 * i + 1];
    double pv[4] = {p01.x, p01.y, p23.x, p23.y};
    double o[4];
#pragma unroll
    for (int k = 0; k < 4; ++k) {
        double mean = stats_s[k] * (1.0 / 8192.0);
        double var  = stats_s[4 + k] * (1.0 / 8192.0) - mean * mean;
        double inv  = 1.0 / sqrt(var + 1e-5);
        o[k] = (pv[k] - mean) * inv * (double)gamma[k] + (double)beta[k];
    }
    double nrm = sqrt(o[0] * o[0] + o[1] * o[1] + o[2] * o[2] + o[3] * o[3]);
    double innv = 1.0 / (nrm + 1e-12);
    ((float4*)pb32)[i] = make_float4((float)o[0], (float)o[1], (float)o[2], (float)o[3]);
    double n0 = o[0] * innv, n1 = o[1] * innv, n2 = o[2] * innv, n3 = o[3] * innv;
    ((float4*)pn32)[i] = make_float4((float)n0, (float)n1, (float)n2, (float)n3);
    double2* pd = (double2*)(pn64 + (size_t)i * 4);
    pd[0] = make_double2(n0, n1);
    pd[1] = make_double2(n2, n3);
}

// ---------------------------------------------------------------------------
// Kernel 4: O(B^2) adjacency. fp32 fast path, +-2e-4 guard band with f64
// recheck. 32 rows/block (2 rows/lane x 16 j-lanes) -> 256 blocks.
// ---------------------------------------------------------------------------
#define CHUNK 1024
__global__ __launch_bounds__(256) void adj_kernel(
    const float* __restrict__ pn32, const float* __restrict__ pb32,
    const double* __restrict__ pn64,
    float* __restrict__ wp32, float* __restrict__ sd) {

    __shared__ __align__(16) float4 pns[CHUNK];
    __shared__ __align__(16) float4 pbs[CHUNK];
    __shared__ float bpart[16];

    const int t = threadIdx.x;
    const int tg = t & 15, g = t >> 4;
    const int rowb = blockIdx.x * 32 + g * 2;

    float4 pni[2];
#pragma unroll
    for (int r = 0; r < 2; ++r) pni[r] = ((const float4*)pn32)[rowb + r];
    float w[2][4] = {};

    for (int base = 0; base < 8192; base += CHUNK) {
        __syncthreads();
        for (int i = t; i < CHUNK; i += 256) {
            pns[i] = ((const float4*)pn32)[base + i];
            pbs[i] = ((const float4*)pb32)[base + i];
        }
        __syncthreads();
        for (int jj = 0; jj < CHUNK / 16; ++jj) {
            const int jl = jj * 16 + tg;
            const int j = base + jl;
            float4 q = pns[jl];
            float4 pj = pbs[jl];
#pragma unroll
            for (int r = 0; r < 2; ++r) {
                float d = fmaf(pni[r].x, q.x, fmaf(pni[r].y, q.y,
                          fmaf(pni[r].z, q.z, pni[r].w * q.w)));
                float fid = d * d;
                bool ok;
                if (fabsf(fid - 0.9f) < 2e-4f) {   // rare: exact recheck
                    const double2* pr = (const double2*)(pn64 + (size_t)(rowb + r) * 4);
                    const double2* pq = (const double2*)(pn64 + (size_t)j * 4);
                    double2 r0 = pr[0], r1 = pr[1], q0 = pq[0], q1 = pq[1];
                    double dd = fma(r0.x, q0.x, fma(r0.y, q0.y,
                                fma(r1.x, q1.x, r1.y * q1.y)));
                    ok = (dd * dd >= 0.9);
                } else {
                    ok = (fid >= 0.9f);
                }
                float m = (ok && j != (rowb + r)) ? 1.f : 0.f;
                w[r][0] = fmaf(m, pj.x, w[r][0]);
                w[r][1] = fmaf(m, pj.y, w[r][1]);
                w[r][2] = fmaf(m, pj.z, w[r][2]);
                w[r][3] = fmaf(m, pj.w, w[r][3]);
            }
        }
    }
#pragma unroll
    for (int m = 1; m < 16; m <<= 1)
#pragma unroll
        for (int r = 0; r < 2; ++r) {
            w[r][0] += __shfl_xor(w[r][0], m);
            w[r][1] += __shfl_xor(w[r][1], m);
            w[r][2] += __shfl_xor(w[r][2], m);
            w[r][3] += __shfl_xor(w[r][3], m);
        }
    if (tg == 0) {
        float ds_ = 0.f;
#pragma unroll
        for (int r = 0; r < 2; ++r) {
            ((float4*)wp32)[rowb + r] = make_float4(w[r][0], w[r][1], w[r][2], w[r][3]);
            float4 pbv = ((const float4*)pb32)[rowb + r];
            float d0 = pbv.x - w[r][0], d1 = pbv.y - w[r][1];
            float d2 = pbv.z - w[r][2], d3 = pbv.w - w[r][3];
            ds_ += d0 * d0 + d1 * d1 + d2 * d2 + d3 * d3;
        }
        bpart[g] = ds_;
    }
    __syncthreads();
    if (t == 0) {
        float sacc = 0.f;
#pragma unroll
        for (int i = 0; i < 16; ++i) sacc += bpart[i];
        atomicAdd(sd, sacc);
    }
}

// ---------------------------------------------------------------------------
// Kernel 5: epilogue -> probs
// ---------------------------------------------------------------------------
__global__ __launch_bounds__(256) void final_kernel(
    const float* __restrict__ pb32, const float* __restrict__ wp32,
    const float* __restrict__ sd, float* __restrict__ out) {

    const int i = blockIdx.x * 256 + threadIdx.x;
    const double kv = exp(-(double)sd[0]);
    float4 p = ((const float4*)pb32)[i];
    float4 w = ((const float4*)wp32)[i];
    double logit = (double)p.x + p.y + p.z + p.w
                 + (double)w.x + w.y + w.z + w.w + kv;
    double pr = 1.0 / (1.0 + exp(-logit));
    *(float2*)&out[2 * i] = make_float2((float)pr, (float)(1.0 - pr));
}

// ---------------------------------------------------------------------------
extern "C" void kernel_launch(void* const* d_in, const int* in_sizes, int n_in,
                              void* d_out, int out_size, void* d_ws, size_t ws_size,
                              hipStream_t stream) {
    const float* x     = (const float*)d_in[0];
    const float* c1w   = (const float*)d_in[1];
    const float* c1b   = (const float*)d_in[2];
    const float* c2w   = (const float*)d_in[3];
    const float* c2b   = (const float*)d_in[4];
    const float* fc1w  = (const float*)d_in[5];
    const float* fc1b  = (const float*)d_in[6];
    const float* fc2w  = (const float*)d_in[7];
    const float* fc2b  = (const float*)d_in[8];
    const float* gamma = (const float*)d_in[9];
    const float* beta  = (const float*)d_in[10];
    float* out = (float*)d_out;

    char* ws = (char*)d_ws;
    float*  sd    = (float*)(ws + OFF_SD);
    double* proj  = (double*)(ws + OFF_PROJ);
    double* pn64  = (double*)(ws + OFF_PN64);
    float*  pb32  = (float*)(ws + OFF_PB32);
    float*  pn32  = (float*)(ws + OFF_PN32);
    float*  wp32  = (float*)(ws + OFF_WP32);
    float*  w1t   = (float*)(ws + OFF_W1T);
    double* psum  = (double*)(ws + OFF_PSUM);
    void*   flat  = (void*)(ws + OFF_FLAT);

    // deterministic per-deployment branch (ws_size constant across calls)
    const bool f64flat = ws_size >= (size_t)OFF_FLAT + FLAT64_BYTES;

    setup_kernel<<<64, 256, 0, stream>>>(fc1w, w1t, sd);
    if (f64flat) {
        conv_fused<true><<<B_IMG, 256, 0, stream>>>(x, c1w, c1b, c2w, c2b, flat);
        fc_kernel<true><<<FC_NBLK, 256, 0, stream>>>(flat, w1t, fc1b, fc2w, fc2b, proj, psum);
    } else {
        conv_fused<false><<<B_IMG, 256, 0, stream>>>(x, c1w, c1b, c2w, c2b, flat);
        fc_kernel<false><<<FC_NBLK, 256, 0, stream>>>(flat, w1t, fc1b, fc2w, fc2b, proj, psum);
    }
    bn_kernel<<<B_IMG / 256, 256, 0, stream>>>(proj, psum, gamma, beta, pb32, pn32, pn64);
    adj_kernel<<<B_IMG / 32, 256, 0, stream>>>(pn32, pb32, pn64, wp32, sd);
    final_kernel<<<B_IMG / 256, 256, 0, stream>>>(pb32, wp32, sd, out);
}

// Round 7
// 357.330 us; speedup vs baseline: 1.4140x; 1.3385x over previous
//
#include <hip/hip_runtime.h>
#include <hip/hip_bf16.h>

#define B_IMG 8192
#define FC_ROWS 8
#define FC_NBLK (B_IMG / FC_ROWS)   // 1024

// ---- ws layout (bytes) ----
#define OFF_SD    64                       // 1 float (RBF sum of squares)
#define OFF_PROJ  128                      // 8192*4 doubles = 262144
#define OFF_PN64  (128 + 262144)           // 8192*4 doubles
#define OFF_PB32  (OFF_PN64 + 262144)      // 8192*4 floats
#define OFF_PN32  (OFF_PB32 + 131072)
#define OFF_WP32  (OFF_PN32 + 131072)
#define OFF_W1T   (OFF_WP32 + 131072)      // 784*64 floats = 200704
#define OFF_PSUM  (OFF_W1T + 200704)       // 1024*8 doubles = 65536
#define OFF_FLAT  1310720                  // flat: f64 (51.4MB) or f32 fallback
#define FLAT64_BYTES (8192UL * 784UL * 8UL)

// h1 LDS geometry: 16 rows x 16 cells, cell = 8 doubles @ stride 10,
// row pitch 164 doubles -> conflict-free ds_read_b128 (proven r6: 76M -> 1M).
#define H1_CS   10
#define H1_RP   164

// ---------------------------------------------------------------------------
// Kernel 0: setup — zero sd; transpose fc1w -> w1t[k][o] (f32). 64 blocks.
// ---------------------------------------------------------------------------
__global__ __launch_bounds__(256) void setup_kernel(
    const float* __restrict__ fc1w, float* __restrict__ w1t,
    float* __restrict__ sd) {
    const int t = threadIdx.x;
    if (blockIdx.x == 0 && t == 0) sd[0] = 0.f;
    for (int i = blockIdx.x * 256 + t; i < 784 * 64; i += 64 * 256) {
        const int o = i & 63, k = i >> 6;
        w1t[i] = fc1w[o * 784 + k];     // w1t[k*64+o]
    }
}

// ---------------------------------------------------------------------------
// conv2 helpers: compile-time buffer index (no runtime-indexed reg arrays).
// W[buf][row][colslot][lo/hi] holds a 4x4-cell window.
// ---------------------------------------------------------------------------
template <int BUF>
__device__ __forceinline__ void ldpair(
    double2 (&W)[2][4][2][2], const double* __restrict__ h1s,
    int rowb, int c0, int icp) {
#pragma unroll
    for (int wr = 0; wr < 4; ++wr) {
#pragma unroll
        for (int cc = 0; cc < 2; ++cc) {
            const double* p = h1s + (rowb + wr) * H1_RP + (c0 + cc) * H1_CS + icp * 4;
            W[BUF][wr][cc][0] = *(const double2*)p;
            W[BUF][wr][cc][1] = *(const double2*)(p + 2);
        }
    }
}

template <int PHASE>
__device__ __forceinline__ void conv2_step(
    const double2 (&W)[2][4][2][2], const double (&wgt)[9][4],
    double bias2, int c2, int icp, int pys, int px,
    double* __restrict__ h2s) {
    double s00 = 0, s01 = 0, s10 = 0, s11 = 0;
#pragma unroll
    for (int dy = 0; dy < 2; ++dy)
#pragma unroll
        for (int dx = 0; dx < 2; ++dx)
#pragma unroll
            for (int ky = 0; ky < 3; ++ky)
#pragma unroll
                for (int kx = 0; kx < 3; ++kx) {
                    const int wr = dy + ky, wc = dx + kx;
                    const int buf = (wc < 2) ? PHASE : (1 - PHASE);
                    const int sl = wc & 1;
                    double2 lo = W[buf][wr][sl][0];
                    double2 hi = W[buf][wr][sl][1];
                    double a = (dy == 0) ? ((dx == 0) ? s00 : s01)
                                         : ((dx == 0) ? s10 : s11);
                    a = fma(lo.x, wgt[ky * 3 + kx][0], a);
                    a = fma(lo.y, wgt[ky * 3 + kx][1], a);
                    a = fma(hi.x, wgt[ky * 3 + kx][2], a);
                    a = fma(hi.y, wgt[ky * 3 + kx][3], a);
                    if (dy == 0) { if (dx == 0) s00 = a; else s01 = a; }
                    else         { if (dx == 0) s10 = a; else s11 = a; }
                }
    // combine ic halves (partner lane t^16, same wave, same pys)
    s00 += __shfl_xor(s00, 16);
    s01 += __shfl_xor(s01, 16);
    s10 += __shfl_xor(s10, 16);
    s11 += __shfl_xor(s11, 16);
    if (icp == 0) {
        double mx = fmax(fmax(s00, s01), fmax(s10, s11));
        h2s[c2 * 49 + pys * 7 + px] = fmax(bias2 + mx, 0.0);
    }
}

// ---------------------------------------------------------------------------
// Kernel 1: fused conv1+relu+pool -> conv2+relu+pool, all f64 compute.
// r6 structure (proven: 1M bank conflicts, 164us) + halo-only h1s zeroing.
// ---------------------------------------------------------------------------
template <bool F64OUT>
__global__ __launch_bounds__(256) void conv_fused(
    const float* __restrict__ x,
    const float* __restrict__ w1, const float* __restrict__ b1,
    const float* __restrict__ w2, const float* __restrict__ b2,
    void* __restrict__ flatv) {

    __shared__ __align__(16) float  xs[900];            // padded 30x30 f32
    __shared__ __align__(16) double h1s[16 * H1_RP];    // padded 14x14, strided
    __shared__ __align__(16) double h2s[784];           // [c][7][7]

    const int b = blockIdx.x;
    const int t = threadIdx.x;
    const float* xb = x + (size_t)b * 784;

    const int c2 = t & 15, icp = (t >> 4) & 1, pys = t >> 5;   // pys 0..7
    double wgt[9][4];
#pragma unroll
    for (int m = 0; m < 4; ++m) {
        const float* wsrc = w2 + c2 * 72 + (icp * 4 + m) * 9;
#pragma unroll
        for (int j = 0; j < 9; ++j) wgt[j][m] = (double)wsrc[j];
    }
    const double bias2 = (double)b2[c2];

    // phase A: zero xs + ONLY the h1s halo cells (60 cells x 8 ic)
    for (int i = t; i < 900; i += 256) xs[i] = 0.f;
    for (int i = t; i < 480; i += 256) {
        const int cell = i >> 3, ic = i & 7;
        int r, c;
        if (cell < 16)      { r = 0;  c = cell; }
        else if (cell < 32) { r = 15; c = cell - 16; }
        else if (cell < 46) { r = cell - 31; c = 0; }   // rows 1..14, col 0
        else                { r = cell - 45; c = 15; }  // rows 1..14, col 15
        h1s[r * H1_RP + c * H1_CS + ic] = 0.0;
    }
    __syncthreads();
    // phase B: fill xs interior
    for (int i = t; i < 784; i += 256) {
        const int yy = i / 28, xx = i - yy * 28;
        xs[(yy + 1) * 30 + (xx + 1)] = xb[i];
    }
    __syncthreads();

    // ---- stage 1: conv1 + relu + maxpool (f64) -> h1s interior
    {
        const int c1 = t & 7;
        double wc[9];
#pragma unroll
        for (int j = 0; j < 9; ++j) wc[j] = (double)w1[c1 * 9 + j];
        const double bb = (double)b1[c1];
        for (int q = (t >> 3); q < 196; q += 32) {
            const int py = q / 14, px = q - py * 14;
            double r2[4][4];
#pragma unroll
            for (int rr = 0; rr < 4; ++rr)
#pragma unroll
                for (int cc = 0; cc < 4; ++cc)
                    r2[rr][cc] = (double)xs[(2 * py + rr) * 30 + 2 * px + cc];
            double s[2][2] = {{bb, bb}, {bb, bb}};
#pragma unroll
            for (int dy = 0; dy < 2; ++dy)
#pragma unroll
                for (int dx = 0; dx < 2; ++dx)
#pragma unroll
                    for (int ky = 0; ky < 3; ++ky)
#pragma unroll
                        for (int kx = 0; kx < 3; ++kx)
                            s[dy][dx] = fma(r2[dy + ky][dx + kx], wc[ky * 3 + kx], s[dy][dx]);
            double mx = fmax(fmax(s[0][0], s[0][1]), fmax(s[1][0], s[1][1]));
            mx = fmax(mx, 0.0);   // pool(relu) == relu(maxpool), exactly
            h1s[(py + 1) * H1_RP + (px + 1) * H1_CS + c1] = mx;
        }
    }
    __syncthreads();

    // ---- stage 2: conv2 + relu + maxpool (f64), strip per lane
    if (pys < 7) {
        const int rowb = 2 * pys;     // h1 rows rowb..rowb+3
        double2 W[2][4][2][2];
        ldpair<0>(W, h1s, rowb, 0, icp);
        ldpair<1>(W, h1s, rowb, 2, icp);
#pragma unroll
        for (int px = 0; px < 7; ++px) {
            if ((px & 1) == 0) {
                conv2_step<0>(W, wgt, bias2, c2, icp, pys, px, h2s);
                if (px < 6) ldpair<0>(W, h1s, rowb, 2 * px + 4, icp);
            } else {
                conv2_step<1>(W, wgt, bias2, c2, icp, pys, px, h2s);
                if (px < 6) ldpair<1>(W, h1s, rowb, 2 * px + 4, icp);
            }
        }
    }
    __syncthreads();

    // coalesced writeout of the flat row
    if (F64OUT) {
        double2* dst = (double2*)((double*)flatv + (size_t)b * 784);
        const double2* src = (const double2*)h2s;
        for (int i = t; i < 392; i += 256) dst[i] = src[i];
    } else {
        float* dst = (float*)flatv + (size_t)b * 784;
        for (int i = t; i < 784; i += 256) dst[i] = (float)h2s[i];
    }
}

// ---------------------------------------------------------------------------
// Kernel 2: FC1 (784->64, relu) + FC2 (64->4) + BN stat partials.
// 1024 blocks x 256 thr; 8 rows LDS-staged (one contiguous double2 copy —
// rows are consecutive in flat); thread = (o, wave) computes 2 rows (acc x2)
// -> each wave's 200KB w1t L2 read amortizes over 2 rows (traffic halved vs
// r5, staging restored after r6's wave-uniform-global regression).
// ---------------------------------------------------------------------------
template <bool F64IN>
__global__ __launch_bounds__(256) void fc_kernel(
    const void* __restrict__ flatv, const float* __restrict__ w1t,
    const float* __restrict__ fc1b,
    const float* __restrict__ fc2w, const float* __restrict__ fc2b,
    double* __restrict__ proj, double* __restrict__ psum) {

    __shared__ __align__(16) double rows[FC_ROWS][784];
    __shared__ __align__(16) double Hs[FC_ROWS][64];
    __shared__ double w2t[256];   // [o][kc] fc2 transposed

    const int t = threadIdx.x;
    const int row0 = blockIdx.x * FC_ROWS;

    w2t[t] = (double)fc2w[(t & 3) * 64 + (t >> 2)];
    // stage 8 contiguous rows (6272 doubles) as double2 — fully coalesced
    if (F64IN) {
        const double2* src = (const double2*)((const double*)flatv + (size_t)row0 * 784);
        double2* dst = (double2*)&rows[0][0];
        for (int i = t; i < FC_ROWS * 784 / 2; i += 256) dst[i] = src[i];
    } else {
        const float4* src = (const float4*)((const float*)flatv + (size_t)row0 * 784);
        double* dst = &rows[0][0];
        for (int i = t; i < FC_ROWS * 784 / 4; i += 256) {
            float4 f = src[i];
            dst[4 * i + 0] = (double)f.x; dst[4 * i + 1] = (double)f.y;
            dst[4 * i + 2] = (double)f.z; dst[4 * i + 3] = (double)f.w;
        }
    }
    __syncthreads();

    const int o = t & 63, s2 = (t >> 6) * 2;
    const double* rp0 = rows[s2];
    const double* rp1 = rows[s2 + 1];
    double a00 = 0.0, a01 = 0.0, a10 = 0.0, a11 = 0.0;
    for (int k = 0; k < 784; k += 4) {
        double2 p0a = *(const double2*)&rp0[k];
        double2 p0b = *(const double2*)&rp0[k + 2];
        double2 p1a = *(const double2*)&rp1[k];
        double2 p1b = *(const double2*)&rp1[k + 2];
        const double wa = (double)w1t[(k + 0) * 64 + o];
        const double wb = (double)w1t[(k + 1) * 64 + o];
        const double wc = (double)w1t[(k + 2) * 64 + o];
        const double wd = (double)w1t[(k + 3) * 64 + o];
        a00 = fma(p0a.x, wa, a00);
        a01 = fma(p0a.y, wb, a01);
        a00 = fma(p0b.x, wc, a00);
        a01 = fma(p0b.y, wd, a01);
        a10 = fma(p1a.x, wa, a10);
        a11 = fma(p1a.y, wb, a11);
        a10 = fma(p1b.x, wc, a10);
        a11 = fma(p1b.y, wd, a11);
    }
    const double b1v = (double)fc1b[o];
    Hs[s2][o]     = fmax((a00 + a01) + b1v, 0.0);   // same per-row order as r5/r6
    Hs[s2 + 1][o] = fmax((a10 + a11) + b1v, 0.0);
    __syncthreads();

    if (t < 32) {
        const int r = t >> 2, kc = t & 3;
        double sv = (double)fc2b[kc];
#pragma unroll 8
        for (int c = 0; c < 64; ++c) sv = fma(Hs[r][c], w2t[c * 4 + kc], sv);
        proj[(size_t)(row0 + r) * 4 + kc] = sv;
        double ssum = sv, sq = sv * sv;
        ssum += __shfl_xor(ssum, 4);   sq += __shfl_xor(sq, 4);
        ssum += __shfl_xor(ssum, 8);   sq += __shfl_xor(sq, 8);
        ssum += __shfl_xor(ssum, 16);  sq += __shfl_xor(sq, 16);
        if (t < 4) {
            psum[(size_t)blockIdx.x * 8 + t] = ssum;
            psum[(size_t)blockIdx.x * 8 + 4 + t] = sq;
        }
    }
}

// ---------------------------------------------------------------------------
// Kernel 3: stats-reduce (replicated per block, deterministic order) +
// BatchNorm + row L2-normalize, f64. Emits pb32/pn32 + pn64.
// ---------------------------------------------------------------------------
__global__ __launch_bounds__(256) void bn_kernel(
    const double* __restrict__ proj, const double* __restrict__ psum,
    const float* __restrict__ gamma, const float* __restrict__ beta,
    float* __restrict__ pb32, float* __restrict__ pn32,
    double* __restrict__ pn64) {

    __shared__ double red[256];
    __shared__ double stats_s[8];
    const int t = threadIdx.x;
    {
        const int c = t & 7, i0 = t >> 3;
        double v = 0.0;
        for (int i = i0; i < FC_NBLK; i += 32) v += psum[(size_t)i * 8 + c];
        red[t] = v;
    }
    __syncthreads();
    if (t < 8) {
        double sacc = 0.0;
        for (int j = 0; j < 32; ++j) sacc += red[t + 8 * j];
        stats_s[t] = sacc;
    }
    __syncthreads();

    const int i = blockIdx.x * 256 + t;
    double2 p01 = ((const double2*)proj)[2 * i];
    double2 p23 = ((const double2*)proj)[2 * i + 1];
    double pv[4] = {p01.x, p01.y, p23.x, p23.y};
    double o[4];
#pragma unroll
    for (int k = 0; k < 4; ++k) {
        double mean = stats_s[k] * (1.0 / 8192.0);
        double var  = stats_s[4 + k] * (1.0 / 8192.0) - mean * mean;
        double inv  = 1.0 / sqrt(var + 1e-5);
        o[k] = (pv[k] - mean) * inv * (double)gamma[k] + (double)beta[k];
    }
    double nrm = sqrt(o[0] * o[0] + o[1] * o[1] + o[2] * o[2] + o[3] * o[3]);
    double innv = 1.0 / (nrm + 1e-12);
    ((float4*)pb32)[i] = make_float4((float)o[0], (float)o[1], (float)o[2], (float)o[3]);
    double n0 = o[0] * innv, n1 = o[1] * innv, n2 = o[2] * innv, n3 = o[3] * innv;
    ((float4*)pn32)[i] = make_float4((float)n0, (float)n1, (float)n2, (float)n3);
    double2* pd = (double2*)(pn64 + (size_t)i * 4);
    pd[0] = make_double2(n0, n1);
    pd[1] = make_double2(n2, n3);
}

// ---------------------------------------------------------------------------
// Kernel 4: O(B^2) adjacency. fp32 fast path, +-2e-4 guard band with f64
// recheck. 512 blocks x 16 rows (1 row per 16-lane group) -> 2 blocks/CU.
// Diagonal trick: fid(i,i)=1>=0.9 always, so accumulate ALL j and subtract
// pb_i after the reduce — removes the j!=row test from the hot loop.
// ---------------------------------------------------------------------------
#define CHUNK 1024
__global__ __launch_bounds__(256) void adj_kernel(
    const float* __restrict__ pn32, const float* __restrict__ pb32,
    const double* __restrict__ pn64,
    float* __restrict__ wp32, float* __restrict__ sd) {

    __shared__ __align__(16) float4 pns[CHUNK];
    __shared__ __align__(16) float4 pbs[CHUNK];
    __shared__ float bpart[16];

    const int t = threadIdx.x;
    const int tg = t & 15, g = t >> 4;
    const int row = blockIdx.x * 16 + g;

    const float4 pni = ((const float4*)pn32)[row];
    float w0 = 0.f, w1 = 0.f, w2 = 0.f, w3 = 0.f;

    for (int base = 0; base < 8192; base += CHUNK) {
        for (int i = t; i < CHUNK; i += 256) {
            pns[i] = ((const float4*)pn32)[base + i];
            pbs[i] = ((const float4*)pb32)[base + i];
        }
        __syncthreads();
        for (int jj = 0; jj < CHUNK / 16; ++jj) {
            const int jl = jj * 16 + tg;
            float4 q = pns[jl];
            float4 pj = pbs[jl];
            float d = fmaf(pni.x, q.x, fmaf(pni.y, q.y,
                      fmaf(pni.z, q.z, pni.w * q.w)));
            float fid = d * d;
            float tdiff = fid - 0.9f;
            bool ok;
            if (fabsf(tdiff) < 2e-4f) {   // rare: exact recheck
                const int j = base + jl;
                const double2* pr = (const double2*)(pn64 + (size_t)row * 4);
                const double2* pq = (const double2*)(pn64 + (size_t)j * 4);
                double2 r0 = pr[0], r1 = pr[1], q0 = pq[0], q1 = pq[1];
                double dd = fma(r0.x, q0.x, fma(r0.y, q0.y,
                            fma(r1.x, q1.x, r1.y * q1.y)));
                ok = (dd * dd >= 0.9);
            } else {
                ok = (tdiff >= 0.f);
            }
            float m = ok ? 1.f : 0.f;
            w0 = fmaf(m, pj.x, w0);
            w1 = fmaf(m, pj.y, w1);
            w2 = fmaf(m, pj.z, w2);
            w3 = fmaf(m, pj.w, w3);
        }
        __syncthreads();
    }
#pragma unroll
    for (int msk = 1; msk < 16; msk <<= 1) {
        w0 += __shfl_xor(w0, msk);
        w1 += __shfl_xor(w1, msk);
        w2 += __shfl_xor(w2, msk);
        w3 += __shfl_xor(w3, msk);
    }
    if (tg == 0) {
        float4 pbv = ((const float4*)pb32)[row];
        w0 -= pbv.x; w1 -= pbv.y; w2 -= pbv.z; w3 -= pbv.w;  // remove diagonal
        ((float4*)wp32)[row] = make_float4(w0, w1, w2, w3);
        float d0 = pbv.x - w0, d1 = pbv.y - w1, d2_ = pbv.z - w2, d3 = pbv.w - w3;
        bpart[g] = d0 * d0 + d1 * d1 + d2_ * d2_ + d3 * d3;
    }
    __syncthreads();
    if (t == 0) {
        float sacc = 0.f;
#pragma unroll
        for (int i = 0; i < 16; ++i) sacc += bpart[i];
        atomicAdd(sd, sacc);
    }
}

// ---------------------------------------------------------------------------
// Kernel 5: epilogue -> probs
// ---------------------------------------------------------------------------
__global__ __launch_bounds__(256) void final_kernel(
    const float* __restrict__ pb32, const float* __restrict__ wp32,
    const float* __restrict__ sd, float* __restrict__ out) {

    const int i = blockIdx.x * 256 + threadIdx.x;
    const double kv = exp(-(double)sd[0]);
    float4 p = ((const float4*)pb32)[i];
    float4 w = ((const float4*)wp32)[i];
    double logit = (double)p.x + p.y + p.z + p.w
                 + (double)w.x + w.y + w.z + w.w + kv;
    double pr = 1.0 / (1.0 + exp(-logit));
    *(float2*)&out[2 * i] = make_float2((float)pr, (float)(1.0 - pr));
}

// ---------------------------------------------------------------------------
extern "C" void kernel_launch(void* const* d_in, const int* in_sizes, int n_in,
                              void* d_out, int out_size, void* d_ws, size_t ws_size,
                              hipStream_t stream) {
    const float* x     = (const float*)d_in[0];
    const float* c1w   = (const float*)d_in[1];
    const float* c1b   = (const float*)d_in[2];
    const float* c2w   = (const float*)d_in[3];
    const float* c2b   = (const float*)d_in[4];
    const float* fc1w  = (const float*)d_in[5];
    const float* fc1b  = (const float*)d_in[6];
    const float* fc2w  = (const float*)d_in[7];
    const float* fc2b  = (const float*)d_in[8];
    const float* gamma = (const float*)d_in[9];
    const float* beta  = (const float*)d_in[10];
    float* out = (float*)d_out;

    char* ws = (char*)d_ws;
    float*  sd    = (float*)(ws + OFF_SD);
    double* proj  = (double*)(ws + OFF_PROJ);
    double* pn64  = (double*)(ws + OFF_PN64);
    float*  pb32  = (float*)(ws + OFF_PB32);
    float*  pn32  = (float*)(ws + OFF_PN32);
    float*  wp32  = (float*)(ws + OFF_WP32);
    float*  w1t   = (float*)(ws + OFF_W1T);
    double* psum  = (double*)(ws + OFF_PSUM);
    void*   flat  = (void*)(ws + OFF_FLAT);

    // deterministic per-deployment branch (ws_size constant across calls)
    const bool f64flat = ws_size >= (size_t)OFF_FLAT + FLAT64_BYTES;

    setup_kernel<<<64, 256, 0, stream>>>(fc1w, w1t, sd);
    if (f64flat) {
        conv_fused<true><<<B_IMG, 256, 0, stream>>>(x, c1w, c1b, c2w, c2b, flat);
        fc_kernel<true><<<FC_NBLK, 256, 0, stream>>>(flat, w1t, fc1b, fc2w, fc2b, proj, psum);
    } else {
        conv_fused<false><<<B_IMG, 256, 0, stream>>>(x, c1w, c1b, c2w, c2b, flat);
        fc_kernel<false><<<FC_NBLK, 256, 0, stream>>>(flat, w1t, fc1b, fc2w, fc2b, proj, psum);
    }
    bn_kernel<<<B_IMG / 256, 256, 0, stream>>>(proj, psum, gamma, beta, pb32, pn32, pn64);
    adj_kernel<<<B_IMG / 16, 256, 0, stream>>>(pn32, pb32, pn64, wp32, sd);
    final_kernel<<<B_IMG / 256, 256, 0, stream>>>(pb32, wp32, sd, out);
}

// Round 8
// 356.256 us; speedup vs baseline: 1.4183x; 1.0030x over previous
//
#include <hip/hip_runtime.h>
#include <hip/hip_bf16.h>

#define B_IMG 8192
#define FC_ROWS 8
#define FC_NBLK (B_IMG / FC_ROWS)   // 1024

// ---- ws layout (bytes) ----
#define OFF_SD    64                       // 1 float (RBF sum of squares)
#define OFF_PROJ  128                      // 8192*4 doubles = 262144
#define OFF_PN64  (128 + 262144)           // 8192*4 doubles
#define OFF_PB32  (OFF_PN64 + 262144)      // 8192*4 floats
#define OFF_PN32  (OFF_PB32 + 131072)
#define OFF_WP32  (OFF_PN32 + 131072)
#define OFF_W1T   (OFF_WP32 + 131072)      // 784*64 floats = 200704
#define OFF_PSUM  (OFF_W1T + 200704)       // 1024*8 doubles = 65536
#define OFF_FLAT  1310720                  // flat: f64 (51.4MB) or f32 fallback
#define FLAT64_BYTES (8192UL * 784UL * 8UL)

// h1 LDS geometry: 16 rows x 16 cells, cell = 8 doubles @ stride 10,
// row pitch 164 doubles -> conflict-free ds_read_b128 (proven r6/r7: ~1M).
#define H1_CS   10
#define H1_RP   164

// ---------------------------------------------------------------------------
// Kernel 0: setup — zero sd; repack fc1w -> w1t4[k/4][o][4] (float4-loadable).
// ---------------------------------------------------------------------------
__global__ __launch_bounds__(256) void setup_kernel(
    const float* __restrict__ fc1w, float* __restrict__ w1t,
    float* __restrict__ sd) {
    const int t = threadIdx.x;
    if (blockIdx.x == 0 && t == 0) sd[0] = 0.f;
    for (int i = blockIdx.x * 256 + t; i < 784 * 64; i += 64 * 256) {
        const int o = i & 63, k = i >> 6;
        w1t[(k >> 2) * 256 + o * 4 + (k & 3)] = fc1w[o * 784 + k];
    }
}

// ---------------------------------------------------------------------------
// conv2 helpers (unchanged from r6/r7 — proven conflict-free).
// ---------------------------------------------------------------------------
template <int BUF>
__device__ __forceinline__ void ldpair(
    double2 (&W)[2][4][2][2], const double* __restrict__ h1s,
    int rowb, int c0, int icp) {
#pragma unroll
    for (int wr = 0; wr < 4; ++wr) {
#pragma unroll
        for (int cc = 0; cc < 2; ++cc) {
            const double* p = h1s + (rowb + wr) * H1_RP + (c0 + cc) * H1_CS + icp * 4;
            W[BUF][wr][cc][0] = *(const double2*)p;
            W[BUF][wr][cc][1] = *(const double2*)(p + 2);
        }
    }
}

template <int PHASE>
__device__ __forceinline__ void conv2_step(
    const double2 (&W)[2][4][2][2], const double (&wgt)[9][4],
    double bias2, int c2, int icp, int pys, int px,
    double* __restrict__ h2s) {
    double s00 = 0, s01 = 0, s10 = 0, s11 = 0;
#pragma unroll
    for (int dy = 0; dy < 2; ++dy)
#pragma unroll
        for (int dx = 0; dx < 2; ++dx)
#pragma unroll
            for (int ky = 0; ky < 3; ++ky)
#pragma unroll
                for (int kx = 0; kx < 3; ++kx) {
                    const int wr = dy + ky, wc = dx + kx;
                    const int buf = (wc < 2) ? PHASE : (1 - PHASE);
                    const int sl = wc & 1;
                    double2 lo = W[buf][wr][sl][0];
                    double2 hi = W[buf][wr][sl][1];
                    double a = (dy == 0) ? ((dx == 0) ? s00 : s01)
                                         : ((dx == 0) ? s10 : s11);
                    a = fma(lo.x, wgt[ky * 3 + kx][0], a);
                    a = fma(lo.y, wgt[ky * 3 + kx][1], a);
                    a = fma(hi.x, wgt[ky * 3 + kx][2], a);
                    a = fma(hi.y, wgt[ky * 3 + kx][3], a);
                    if (dy == 0) { if (dx == 0) s00 = a; else s01 = a; }
                    else         { if (dx == 0) s10 = a; else s11 = a; }
                }
    s00 += __shfl_xor(s00, 16);
    s01 += __shfl_xor(s01, 16);
    s10 += __shfl_xor(s10, 16);
    s11 += __shfl_xor(s11, 16);
    if (icp == 0) {
        double mx = fmax(fmax(s00, s01), fmax(s10, s11));
        h2s[c2 * 49 + pys * 7 + px] = fmax(bias2 + mx, 0.0);
    }
}

// ---------------------------------------------------------------------------
// Kernel 1: fused conv1+relu+pool -> conv2+relu+pool, all f64 compute.
// Stage 1 NEW: each lane computes a PAIR of adjacent pool outputs from a
// shared 4x6 window (12 ds_read_b64, one base addr, 24 shared cvt, 8 chains).
// Per-output FMA order identical to r7 -> bit-exact h1s.
// ---------------------------------------------------------------------------
template <bool F64OUT>
__global__ __launch_bounds__(256) void conv_fused(
    const float* __restrict__ x,
    const float* __restrict__ w1, const float* __restrict__ b1,
    const float* __restrict__ w2, const float* __restrict__ b2,
    void* __restrict__ flatv) {

    __shared__ __align__(16) float  xs[900];            // padded 30x30 f32
    __shared__ __align__(16) double h1s[16 * H1_RP];    // padded 14x14, strided
    __shared__ __align__(16) double h2s[784];           // [c][7][7]

    const int b = blockIdx.x;
    const int t = threadIdx.x;
    const float* xb = x + (size_t)b * 784;

    const int c2 = t & 15, icp = (t >> 4) & 1, pys = t >> 5;   // pys 0..7
    double wgt[9][4];
#pragma unroll
    for (int m = 0; m < 4; ++m) {
        const float* wsrc = w2 + c2 * 72 + (icp * 4 + m) * 9;
#pragma unroll
        for (int j = 0; j < 9; ++j) wgt[j][m] = (double)wsrc[j];
    }
    const double bias2 = (double)b2[c2];

    // phase A: zero xs + ONLY the h1s halo cells (60 cells x 8 ic)
    for (int i = t; i < 900; i += 256) xs[i] = 0.f;
    for (int i = t; i < 480; i += 256) {
        const int cell = i >> 3, ic = i & 7;
        int r, c;
        if (cell < 16)      { r = 0;  c = cell; }
        else if (cell < 32) { r = 15; c = cell - 16; }
        else if (cell < 46) { r = cell - 31; c = 0; }   // rows 1..14, col 0
        else                { r = cell - 45; c = 15; }  // rows 1..14, col 15
        h1s[r * H1_RP + c * H1_CS + ic] = 0.0;
    }
    __syncthreads();
    // phase B: fill xs interior
    for (int i = t; i < 784; i += 256) {
        const int yy = i / 28, xx = i - yy * 28;
        xs[(yy + 1) * 30 + (xx + 1)] = xb[i];
    }
    __syncthreads();

    // ---- stage 1: conv1 + relu + maxpool (f64), PAIRS of outputs per lane
    {
        const int c1 = t & 7;
        const int lq = t >> 3;          // 0..31 pair-slot
        double wc[9];
#pragma unroll
        for (int j = 0; j < 9; ++j) wc[j] = (double)w1[c1 * 9 + j];
        const double bb = (double)b1[c1];
#pragma unroll
        for (int it = 0; it < 4; ++it) {
            const int pp = lq + 32 * it;        // pair index 0..97
            if (pp >= 98) break;
            const int py = pp / 7, pxp = pp - py * 7;
            const int px0 = 2 * pxp;            // left output col (0..12)
            // shared 4x6 window, float2 reads, one base address
            const float* xbase = &xs[(2 * py) * 30 + 2 * px0];
            double dwin[4][6];
#pragma unroll
            for (int rr = 0; rr < 4; ++rr)
#pragma unroll
                for (int cp = 0; cp < 3; ++cp) {
                    float2 v = *(const float2*)&xbase[rr * 30 + 2 * cp];
                    dwin[rr][2 * cp]     = (double)v.x;
                    dwin[rr][2 * cp + 1] = (double)v.y;
                }
            double s0[2][2] = {{bb, bb}, {bb, bb}};   // output px0
            double s1[2][2] = {{bb, bb}, {bb, bb}};   // output px0+1
#pragma unroll
            for (int dy = 0; dy < 2; ++dy)
#pragma unroll
                for (int dx = 0; dx < 2; ++dx)
#pragma unroll
                    for (int ky = 0; ky < 3; ++ky)
#pragma unroll
                        for (int kx = 0; kx < 3; ++kx) {
                            const double wv = wc[ky * 3 + kx];
                            s0[dy][dx] = fma(dwin[dy + ky][dx + kx],     wv, s0[dy][dx]);
                            s1[dy][dx] = fma(dwin[dy + ky][2 + dx + kx], wv, s1[dy][dx]);
                        }
            double mx0 = fmax(fmax(s0[0][0], s0[0][1]), fmax(s0[1][0], s0[1][1]));
            double mx1 = fmax(fmax(s1[0][0], s1[0][1]), fmax(s1[1][0], s1[1][1]));
            mx0 = fmax(mx0, 0.0);
            mx1 = fmax(mx1, 0.0);
            h1s[(py + 1) * H1_RP + (px0 + 1) * H1_CS + c1] = mx0;
            h1s[(py + 1) * H1_RP + (px0 + 2) * H1_CS + c1] = mx1;
        }
    }
    __syncthreads();

    // ---- stage 2: conv2 + relu + maxpool (f64), strip per lane (r6-proven)
    if (pys < 7) {
        const int rowb = 2 * pys;
        double2 W[2][4][2][2];
        ldpair<0>(W, h1s, rowb, 0, icp);
        ldpair<1>(W, h1s, rowb, 2, icp);
#pragma unroll
        for (int px = 0; px < 7; ++px) {
            if ((px & 1) == 0) {
                conv2_step<0>(W, wgt, bias2, c2, icp, pys, px, h2s);
                if (px < 6) ldpair<0>(W, h1s, rowb, 2 * px + 4, icp);
            } else {
                conv2_step<1>(W, wgt, bias2, c2, icp, pys, px, h2s);
                if (px < 6) ldpair<1>(W, h1s, rowb, 2 * px + 4, icp);
            }
        }
    }
    __syncthreads();

    // coalesced writeout of the flat row
    if (F64OUT) {
        double2* dst = (double2*)((double*)flatv + (size_t)b * 784);
        const double2* src = (const double2*)h2s;
        for (int i = t; i < 392; i += 256) dst[i] = src[i];
    } else {
        float* dst = (float*)flatv + (size_t)b * 784;
        for (int i = t; i < 784; i += 256) dst[i] = (float)h2s[i];
    }
}

// ---------------------------------------------------------------------------
// Kernel 2: FC1 (784->64, relu) + FC2 (64->4) + BN stat partials.
// 1024 blocks x 256 thr; 8 rows LDS-staged; w1t4 float4 loads (196 VMEM
// instr/thread vs 784). Same per-row f64 accumulation order as r7.
// ---------------------------------------------------------------------------
template <bool F64IN>
__global__ __launch_bounds__(256) void fc_kernel(
    const void* __restrict__ flatv, const float* __restrict__ w1t,
    const float* __restrict__ fc1b,
    const float* __restrict__ fc2w, const float* __restrict__ fc2b,
    double* __restrict__ proj, double* __restrict__ psum) {

    __shared__ __align__(16) double rows[FC_ROWS][784];
    __shared__ __align__(16) double Hs[FC_ROWS][64];
    __shared__ double w2t[256];   // [o][kc] fc2 transposed

    const int t = threadIdx.x;
    const int row0 = blockIdx.x * FC_ROWS;

    w2t[t] = (double)fc2w[(t & 3) * 64 + (t >> 2)];
    if (F64IN) {
        const double2* src = (const double2*)((const double*)flatv + (size_t)row0 * 784);
        double2* dst = (double2*)&rows[0][0];
        for (int i = t; i < FC_ROWS * 784 / 2; i += 256) dst[i] = src[i];
    } else {
        const float4* src = (const float4*)((const float*)flatv + (size_t)row0 * 784);
        double* dst = &rows[0][0];
        for (int i = t; i < FC_ROWS * 784 / 4; i += 256) {
            float4 f = src[i];
            dst[4 * i + 0] = (double)f.x; dst[4 * i + 1] = (double)f.y;
            dst[4 * i + 2] = (double)f.z; dst[4 * i + 3] = (double)f.w;
        }
    }
    __syncthreads();

    const int o = t & 63, s2 = (t >> 6) * 2;
    const double* rp0 = rows[s2];
    const double* rp1 = rows[s2 + 1];
    const float4* wv4 = (const float4*)w1t;
    double a00 = 0.0, a01 = 0.0, a10 = 0.0, a11 = 0.0;
    for (int k = 0; k < 784; k += 4) {
        double2 p0a = *(const double2*)&rp0[k];
        double2 p0b = *(const double2*)&rp0[k + 2];
        double2 p1a = *(const double2*)&rp1[k];
        double2 p1b = *(const double2*)&rp1[k + 2];
        const float4 wv = wv4[(k >> 2) * 64 + o];
        const double wa = (double)wv.x, wb = (double)wv.y;
        const double wc = (double)wv.z, wd = (double)wv.w;
        a00 = fma(p0a.x, wa, a00);
        a01 = fma(p0a.y, wb, a01);
        a00 = fma(p0b.x, wc, a00);
        a01 = fma(p0b.y, wd, a01);
        a10 = fma(p1a.x, wa, a10);
        a11 = fma(p1a.y, wb, a11);
        a10 = fma(p1b.x, wc, a10);
        a11 = fma(p1b.y, wd, a11);
    }
    const double b1v = (double)fc1b[o];
    Hs[s2][o]     = fmax((a00 + a01) + b1v, 0.0);
    Hs[s2 + 1][o] = fmax((a10 + a11) + b1v, 0.0);
    __syncthreads();

    if (t < 32) {
        const int r = t >> 2, kc = t & 3;
        double sv = (double)fc2b[kc];
#pragma unroll 8
        for (int c = 0; c < 64; ++c) sv = fma(Hs[r][c], w2t[c * 4 + kc], sv);
        proj[(size_t)(row0 + r) * 4 + kc] = sv;
        double ssum = sv, sq = sv * sv;
        ssum += __shfl_xor(ssum, 4);   sq += __shfl_xor(sq, 4);
        ssum += __shfl_xor(ssum, 8);   sq += __shfl_xor(sq, 8);
        ssum += __shfl_xor(ssum, 16);  sq += __shfl_xor(sq, 16);
        if (t < 4) {
            psum[(size_t)blockIdx.x * 8 + t] = ssum;
            psum[(size_t)blockIdx.x * 8 + 4 + t] = sq;
        }
    }
}

// ---------------------------------------------------------------------------
// Kernel 3: stats-reduce (replicated, deterministic) + BatchNorm + row
// L2-normalize, f64. Emits pb32/pn32 + pn64.
// ---------------------------------------------------------------------------
__global__ __launch_bounds__(256) void bn_kernel(
    const double* __restrict__ proj, const double* __restrict__ psum,
    const float* __restrict__ gamma, const float* __restrict__ beta,
    float* __restrict__ pb32, float* __restrict__ pn32,
    double* __restrict__ pn64) {

    __shared__ double red[256];
    __shared__ double stats_s[8];
    const int t = threadIdx.x;
    {
        const int c = t & 7, i0 = t >> 3;
        double v = 0.0;
        for (int i = i0; i < FC_NBLK; i += 32) v += psum[(size_t)i * 8 + c];
        red[t] = v;
    }
    __syncthreads();
    if (t < 8) {
        double sacc = 0.0;
        for (int j = 0; j < 32; ++j) sacc += red[t + 8 * j];
        stats_s[t] = sacc;
    }
    __syncthreads();

    const int i = blockIdx.x * 256 + t;
    double2 p01 = ((const double2*)proj)[2 * i];
    double2 p23 = ((const double2*)proj)[2 * i + 1];
    double pv[4] = {p01.x, p01.y, p23.x, p23.y};
    double o[4];
#pragma unroll
    for (int k = 0; k < 4; ++k) {
        double mean = stats_s[k] * (1.0 / 8192.0);
        double var  = stats_s[4 + k] * (1.0 / 8192.0) - mean * mean;
        double inv  = 1.0 / sqrt(var + 1e-5);
        o[k] = (pv[k] - mean) * inv * (double)gamma[k] + (double)beta[k];
    }
    double nrm = sqrt(o[0] * o[0] + o[1] * o[1] + o[2] * o[2] + o[3] * o[3]);
    double innv = 1.0 / (nrm + 1e-12);
    ((float4*)pb32)[i] = make_float4((float)o[0], (float)o[1], (float)o[2], (float)o[3]);
    double n0 = o[0] * innv, n1 = o[1] * innv, n2 = o[2] * innv, n3 = o[3] * innv;
    ((float4*)pn32)[i] = make_float4((float)n0, (float)n1, (float)n2, (float)n3);
    double2* pd = (double2*)(pn64 + (size_t)i * 4);
    pd[0] = make_double2(n0, n1);
    pd[1] = make_double2(n2, n3);
}

// ---------------------------------------------------------------------------
// Kernel 4: O(B^2) adjacency. fp32 fast path, +-2e-4 guard band, f64 recheck.
// 2 rows per lane (32 rows/block, 256 blocks, 4 blocks/CU): each staged 16-j
// b128 read pair feeds 2 rows -> LDS-pipe traffic halved vs r7.
// ---------------------------------------------------------------------------
#define CHUNK 1024
__global__ __launch_bounds__(256) void adj_kernel(
    const float* __restrict__ pn32, const float* __restrict__ pb32,
    const double* __restrict__ pn64,
    float* __restrict__ wp32, float* __restrict__ sd) {

    __shared__ __align__(16) float4 pns[CHUNK];
    __shared__ __align__(16) float4 pbs[CHUNK];
    __shared__ float bpart[16];

    const int t = threadIdx.x;
    const int tg = t & 15, g = t >> 4;
    const int rowb = blockIdx.x * 32 + g * 2;

    float4 pni[2];
#pragma unroll
    for (int r = 0; r < 2; ++r) pni[r] = ((const float4*)pn32)[rowb + r];
    float w[2][4] = {};

    for (int base = 0; base < 8192; base += CHUNK) {
        for (int i = t; i < CHUNK; i += 256) {
            pns[i] = ((const float4*)pn32)[base + i];
            pbs[i] = ((const float4*)pb32)[base + i];
        }
        __syncthreads();
        for (int jj = 0; jj < CHUNK / 16; ++jj) {
            const int jl = jj * 16 + tg;
            float4 q = pns[jl];
            float4 pj = pbs[jl];
#pragma unroll
            for (int r = 0; r < 2; ++r) {
                float d = fmaf(pni[r].x, q.x, fmaf(pni[r].y, q.y,
                          fmaf(pni[r].z, q.z, pni[r].w * q.w)));
                float fid = d * d;
                float tdiff = fid - 0.9f;
                bool ok;
                if (fabsf(tdiff) < 2e-4f) {   // rare: exact recheck
                    const int j = base + jl;
                    const double2* pr = (const double2*)(pn64 + (size_t)(rowb + r) * 4);
                    const double2* pq = (const double2*)(pn64 + (size_t)j * 4);
                    double2 r0 = pr[0], r1 = pr[1], q0 = pq[0], q1 = pq[1];
                    double dd = fma(r0.x, q0.x, fma(r0.y, q0.y,
                                fma(r1.x, q1.x, r1.y * q1.y)));
                    ok = (dd * dd >= 0.9);
                } else {
                    ok = (tdiff >= 0.f);
                }
                float m = ok ? 1.f : 0.f;
                w[r][0] = fmaf(m, pj.x, w[r][0]);
                w[r][1] = fmaf(m, pj.y, w[r][1]);
                w[r][2] = fmaf(m, pj.z, w[r][2]);
                w[r][3] = fmaf(m, pj.w, w[r][3]);
            }
        }
        __syncthreads();
    }
#pragma unroll
    for (int msk = 1; msk < 16; msk <<= 1)
#pragma unroll
        for (int r = 0; r < 2; ++r) {
            w[r][0] += __shfl_xor(w[r][0], msk);
            w[r][1] += __shfl_xor(w[r][1], msk);
            w[r][2] += __shfl_xor(w[r][2], msk);
            w[r][3] += __shfl_xor(w[r][3], msk);
        }
    if (tg == 0) {
        float ds_ = 0.f;
#pragma unroll
        for (int r = 0; r < 2; ++r) {
            float4 pbv = ((const float4*)pb32)[rowb + r];
            float v0 = w[r][0] - pbv.x, v1 = w[r][1] - pbv.y;   // remove diagonal
            float v2 = w[r][2] - pbv.z, v3 = w[r][3] - pbv.w;
            ((float4*)wp32)[rowb + r] = make_float4(v0, v1, v2, v3);
            float d0 = pbv.x - v0, d1 = pbv.y - v1;
            float d2 = pbv.z - v2, d3 = pbv.w - v3;
            ds_ += d0 * d0 + d1 * d1 + d2 * d2 + d3 * d3;
        }
        bpart[g] = ds_;
    }
    __syncthreads();
    if (t == 0) {
        float sacc = 0.f;
#pragma unroll
        for (int i = 0; i < 16; ++i) sacc += bpart[i];
        atomicAdd(sd, sacc);
    }
}

// ---------------------------------------------------------------------------
// Kernel 5: epilogue -> probs
// ---------------------------------------------------------------------------
__global__ __launch_bounds__(256) void final_kernel(
    const float* __restrict__ pb32, const float* __restrict__ wp32,
    const float* __restrict__ sd, float* __restrict__ out) {

    const int i = blockIdx.x * 256 + threadIdx.x;
    const double kv = exp(-(double)sd[0]);
    float4 p = ((const float4*)pb32)[i];
    float4 w = ((const float4*)wp32)[i];
    double logit = (double)p.x + p.y + p.z + p.w
                 + (double)w.x + w.y + w.z + w.w + kv;
    double pr = 1.0 / (1.0 + exp(-logit));
    *(float2*)&out[2 * i] = make_float2((float)pr, (float)(1.0 - pr));
}

// ---------------------------------------------------------------------------
extern "C" void kernel_launch(void* const* d_in, const int* in_sizes, int n_in,
                              void* d_out, int out_size, void* d_ws, size_t ws_size,
                              hipStream_t stream) {
    const float* x     = (const float*)d_in[0];
    const float* c1w   = (const float*)d_in[1];
    const float* c1b   = (const float*)d_in[2];
    const float* c2w   = (const float*)d_in[3];
    const float* c2b   = (const float*)d_in[4];
    const float* fc1w  = (const float*)d_in[5];
    const float* fc1b  = (const float*)d_in[6];
    const float* fc2w  = (const float*)d_in[7];
    const float* fc2b  = (const float*)d_in[8];
    const float* gamma = (const float*)d_in[9];
    const float* beta  = (const float*)d_in[10];
    float* out = (float*)d_out;

    char* ws = (char*)d_ws;
    float*  sd    = (float*)(ws + OFF_SD);
    double* proj  = (double*)(ws + OFF_PROJ);
    double* pn64  = (double*)(ws + OFF_PN64);
    float*  pb32  = (float*)(ws + OFF_PB32);
    float*  pn32  = (float*)(ws + OFF_PN32);
    float*  wp32  = (float*)(ws + OFF_WP32);
    float*  w1t   = (float*)(ws + OFF_W1T);
    double* psum  = (double*)(ws + OFF_PSUM);
    void*   flat  = (void*)(ws + OFF_FLAT);

    // deterministic per-deployment branch (ws_size constant across calls)
    const bool f64flat = ws_size >= (size_t)OFF_FLAT + FLAT64_BYTES;

    setup_kernel<<<64, 256, 0, stream>>>(fc1w, w1t, sd);
    if (f64flat) {
        conv_fused<true><<<B_IMG, 256, 0, stream>>>(x, c1w, c1b, c2w, c2b, flat);
        fc_kernel<true><<<FC_NBLK, 256, 0, stream>>>(flat, w1t, fc1b, fc2w, fc2b, proj, psum);
    } else {
        conv_fused<false><<<B_IMG, 256, 0, stream>>>(x, c1w, c1b, c2w, c2b, flat);
        fc_kernel<false><<<FC_NBLK, 256, 0, stream>>>(flat, w1t, fc1b, fc2w, fc2b, proj, psum);
    }
    bn_kernel<<<B_IMG / 256, 256, 0, stream>>>(proj, psum, gamma, beta, pb32, pn32, pn64);
    adj_kernel<<<B_IMG / 32, 256, 0, stream>>>(pn32, pb32, pn64, wp32, sd);
    final_kernel<<<B_IMG / 256, 256, 0, stream>>>(pb32, wp32, sd, out);
}

// Round 9
// 320.818 us; speedup vs baseline: 1.5749x; 1.1105x over previous
//
#include <hip/hip_runtime.h>
#include <hip/hip_bf16.h>

#define B_IMG 8192
#define FC_ROWS 8
#define FC_NBLK (B_IMG / FC_ROWS)   // 1024

// ---- ws layout (bytes) ----
// NOTE: wpp (adjacency partials, 2x8192 float4 = 262144 B) REUSES the proj
// region — proj (f64) is last read by bn_kernel, which completes before
// adj_kernel launches (stream order).
#define OFF_PROJ  128                      // 8192*4 doubles = 262144
#define OFF_WPP   OFF_PROJ                 // reuse (see note)
#define OFF_PN64  (128 + 262144)           // 8192*4 doubles
#define OFF_PB32  (OFF_PN64 + 262144)      // 8192*4 floats
#define OFF_PN32  (OFF_PB32 + 131072)
#define OFF_W1T   (OFF_PN32 + 131072)      // 784*64 floats = 200704
#define OFF_PSUM  (OFF_W1T + 200704)       // 1024*8 doubles = 65536
#define OFF_FLAT  1310720                  // flat: f64 (51.4MB) or f32 fallback
#define FLAT64_BYTES (8192UL * 784UL * 8UL)

// h1 LDS geometry: 16 rows x 16 cells, cell = 8 doubles @ stride 10,
// row pitch 164 doubles -> conflict-free ds_read_b128 (proven r6-r8: ~1.2M).
#define H1_CS   10
#define H1_RP   164

// ---------------------------------------------------------------------------
// conv2 helpers (unchanged from r6-r8 — proven conflict-free).
// ---------------------------------------------------------------------------
template <int BUF>
__device__ __forceinline__ void ldpair(
    double2 (&W)[2][4][2][2], const double* __restrict__ h1s,
    int rowb, int c0, int icp) {
#pragma unroll
    for (int wr = 0; wr < 4; ++wr) {
#pragma unroll
        for (int cc = 0; cc < 2; ++cc) {
            const double* p = h1s + (rowb + wr) * H1_RP + (c0 + cc) * H1_CS + icp * 4;
            W[BUF][wr][cc][0] = *(const double2*)p;
            W[BUF][wr][cc][1] = *(const double2*)(p + 2);
        }
    }
}

template <int PHASE>
__device__ __forceinline__ void conv2_step(
    const double2 (&W)[2][4][2][2], const double (&wgt)[9][4],
    double bias2, int c2, int icp, int pys, int px,
    double* __restrict__ h2s) {
    double s00 = 0, s01 = 0, s10 = 0, s11 = 0;
#pragma unroll
    for (int dy = 0; dy < 2; ++dy)
#pragma unroll
        for (int dx = 0; dx < 2; ++dx)
#pragma unroll
            for (int ky = 0; ky < 3; ++ky)
#pragma unroll
                for (int kx = 0; kx < 3; ++kx) {
                    const int wr = dy + ky, wc = dx + kx;
                    const int buf = (wc < 2) ? PHASE : (1 - PHASE);
                    const int sl = wc & 1;
                    double2 lo = W[buf][wr][sl][0];
                    double2 hi = W[buf][wr][sl][1];
                    double a = (dy == 0) ? ((dx == 0) ? s00 : s01)
                                         : ((dx == 0) ? s10 : s11);
                    a = fma(lo.x, wgt[ky * 3 + kx][0], a);
                    a = fma(lo.y, wgt[ky * 3 + kx][1], a);
                    a = fma(hi.x, wgt[ky * 3 + kx][2], a);
                    a = fma(hi.y, wgt[ky * 3 + kx][3], a);
                    if (dy == 0) { if (dx == 0) s00 = a; else s01 = a; }
                    else         { if (dx == 0) s10 = a; else s11 = a; }
                }
    s00 += __shfl_xor(s00, 16);
    s01 += __shfl_xor(s01, 16);
    s10 += __shfl_xor(s10, 16);
    s11 += __shfl_xor(s11, 16);
    if (icp == 0) {
        double mx = fmax(fmax(s00, s01), fmax(s10, s11));
        h2s[c2 * 49 + pys * 7 + px] = fmax(bias2 + mx, 0.0);
    }
}

// ---------------------------------------------------------------------------
// Kernel 1: fused conv1+relu+pool -> conv2+relu+pool, all f64 compute.
// __launch_bounds__(256,2): 256-VGPR budget so stage-2 window (128 VGPR) +
// weights (72 VGPR) stay RESIDENT (r8's 96-VGPR build spilled/reloaded them).
// Blocks 0-63 additionally repack fc1w -> w1t (absorbs old setup_kernel).
// ---------------------------------------------------------------------------
template <bool F64OUT>
__global__ __launch_bounds__(256, 2) void conv_fused(
    const float* __restrict__ x,
    const float* __restrict__ w1, const float* __restrict__ b1,
    const float* __restrict__ w2, const float* __restrict__ b2,
    const float* __restrict__ fc1w, float* __restrict__ w1t,
    void* __restrict__ flatv) {

    __shared__ __align__(16) float  xs[900];            // padded 30x30 f32
    __shared__ __align__(16) double h1s[16 * H1_RP];    // padded 14x14, strided
    __shared__ __align__(16) double h2s[784];           // [c][7][7]

    const int b = blockIdx.x;
    const int t = threadIdx.x;
    const float* xb = x + (size_t)b * 784;

    // absorbed setup: first 64 blocks repack fc1w -> w1t4[k/4][o][4]
    if (b < 64) {
        for (int i = b * 256 + t; i < 784 * 64; i += 64 * 256) {
            const int o = i & 63, k = i >> 6;
            w1t[(k >> 2) * 256 + o * 4 + (k & 3)] = fc1w[o * 784 + k];
        }
    }

    const int c2 = t & 15, icp = (t >> 4) & 1, pys = t >> 5;   // pys 0..7
    double wgt[9][4];
#pragma unroll
    for (int m = 0; m < 4; ++m) {
        const float* wsrc = w2 + c2 * 72 + (icp * 4 + m) * 9;
#pragma unroll
        for (int j = 0; j < 9; ++j) wgt[j][m] = (double)wsrc[j];
    }
    const double bias2 = (double)b2[c2];

    // phase A: zero xs + ONLY the h1s halo cells (60 cells x 8 ic)
    for (int i = t; i < 900; i += 256) xs[i] = 0.f;
    for (int i = t; i < 480; i += 256) {
        const int cell = i >> 3, ic = i & 7;
        int r, c;
        if (cell < 16)      { r = 0;  c = cell; }
        else if (cell < 32) { r = 15; c = cell - 16; }
        else if (cell < 46) { r = cell - 31; c = 0; }   // rows 1..14, col 0
        else                { r = cell - 45; c = 15; }  // rows 1..14, col 15
        h1s[r * H1_RP + c * H1_CS + ic] = 0.0;
    }
    __syncthreads();
    // phase B: fill xs interior
    for (int i = t; i < 784; i += 256) {
        const int yy = i / 28, xx = i - yy * 28;
        xs[(yy + 1) * 30 + (xx + 1)] = xb[i];
    }
    __syncthreads();

    // ---- stage 1: conv1 + relu + maxpool (f64), PAIRS of outputs per lane
    {
        const int c1 = t & 7;
        const int lq = t >> 3;          // 0..31 pair-slot
        double wc[9];
#pragma unroll
        for (int j = 0; j < 9; ++j) wc[j] = (double)w1[c1 * 9 + j];
        const double bb = (double)b1[c1];
#pragma unroll
        for (int it = 0; it < 4; ++it) {
            const int pp = lq + 32 * it;        // pair index 0..97
            if (pp >= 98) break;
            const int py = pp / 7, pxp = pp - py * 7;
            const int px0 = 2 * pxp;            // left output col (0..12)
            const float* xbase = &xs[(2 * py) * 30 + 2 * px0];
            double dwin[4][6];
#pragma unroll
            for (int rr = 0; rr < 4; ++rr)
#pragma unroll
                for (int cp = 0; cp < 3; ++cp) {
                    float2 v = *(const float2*)&xbase[rr * 30 + 2 * cp];
                    dwin[rr][2 * cp]     = (double)v.x;
                    dwin[rr][2 * cp + 1] = (double)v.y;
                }
            double s0[2][2] = {{bb, bb}, {bb, bb}};   // output px0
            double s1[2][2] = {{bb, bb}, {bb, bb}};   // output px0+1
#pragma unroll
            for (int dy = 0; dy < 2; ++dy)
#pragma unroll
                for (int dx = 0; dx < 2; ++dx)
#pragma unroll
                    for (int ky = 0; ky < 3; ++ky)
#pragma unroll
                        for (int kx = 0; kx < 3; ++kx) {
                            const double wv = wc[ky * 3 + kx];
                            s0[dy][dx] = fma(dwin[dy + ky][dx + kx],     wv, s0[dy][dx]);
                            s1[dy][dx] = fma(dwin[dy + ky][2 + dx + kx], wv, s1[dy][dx]);
                        }
            double mx0 = fmax(fmax(s0[0][0], s0[0][1]), fmax(s0[1][0], s0[1][1]));
            double mx1 = fmax(fmax(s1[0][0], s1[0][1]), fmax(s1[1][0], s1[1][1]));
            mx0 = fmax(mx0, 0.0);
            mx1 = fmax(mx1, 0.0);
            h1s[(py + 1) * H1_RP + (px0 + 1) * H1_CS + c1] = mx0;
            h1s[(py + 1) * H1_RP + (px0 + 2) * H1_CS + c1] = mx1;
        }
    }
    __syncthreads();

    // ---- stage 2: conv2 + relu + maxpool (f64), strip per lane (r6-proven)
    if (pys < 7) {
        const int rowb = 2 * pys;
        double2 W[2][4][2][2];
        ldpair<0>(W, h1s, rowb, 0, icp);
        ldpair<1>(W, h1s, rowb, 2, icp);
#pragma unroll
        for (int px = 0; px < 7; ++px) {
            if ((px & 1) == 0) {
                conv2_step<0>(W, wgt, bias2, c2, icp, pys, px, h2s);
                if (px < 6) ldpair<0>(W, h1s, rowb, 2 * px + 4, icp);
            } else {
                conv2_step<1>(W, wgt, bias2, c2, icp, pys, px, h2s);
                if (px < 6) ldpair<1>(W, h1s, rowb, 2 * px + 4, icp);
            }
        }
    }
    __syncthreads();

    // coalesced writeout of the flat row
    if (F64OUT) {
        double2* dst = (double2*)((double*)flatv + (size_t)b * 784);
        const double2* src = (const double2*)h2s;
        for (int i = t; i < 392; i += 256) dst[i] = src[i];
    } else {
        float* dst = (float*)flatv + (size_t)b * 784;
        for (int i = t; i < 784; i += 256) dst[i] = (float)h2s[i];
    }
}

// ---------------------------------------------------------------------------
// Kernel 2: FC1 (784->64, relu) + FC2 (64->4) + BN stat partials.
// Unchanged from r8 (8 rows LDS-staged, w1t4 float4 loads, psum partials).
// ---------------------------------------------------------------------------
template <bool F64IN>
__global__ __launch_bounds__(256) void fc_kernel(
    const void* __restrict__ flatv, const float* __restrict__ w1t,
    const float* __restrict__ fc1b,
    const float* __restrict__ fc2w, const float* __restrict__ fc2b,
    double* __restrict__ proj, double* __restrict__ psum) {

    __shared__ __align__(16) double rows[FC_ROWS][784];
    __shared__ __align__(16) double Hs[FC_ROWS][64];
    __shared__ double w2t[256];   // [o][kc] fc2 transposed

    const int t = threadIdx.x;
    const int row0 = blockIdx.x * FC_ROWS;

    w2t[t] = (double)fc2w[(t & 3) * 64 + (t >> 2)];
    if (F64IN) {
        const double2* src = (const double2*)((const double*)flatv + (size_t)row0 * 784);
        double2* dst = (double2*)&rows[0][0];
        for (int i = t; i < FC_ROWS * 784 / 2; i += 256) dst[i] = src[i];
    } else {
        const float4* src = (const float4*)((const float*)flatv + (size_t)row0 * 784);
        double* dst = &rows[0][0];
        for (int i = t; i < FC_ROWS * 784 / 4; i += 256) {
            float4 f = src[i];
            dst[4 * i + 0] = (double)f.x; dst[4 * i + 1] = (double)f.y;
            dst[4 * i + 2] = (double)f.z; dst[4 * i + 3] = (double)f.w;
        }
    }
    __syncthreads();

    const int o = t & 63, s2 = (t >> 6) * 2;
    const double* rp0 = rows[s2];
    const double* rp1 = rows[s2 + 1];
    const float4* wv4 = (const float4*)w1t;
    double a00 = 0.0, a01 = 0.0, a10 = 0.0, a11 = 0.0;
    for (int k = 0; k < 784; k += 4) {
        double2 p0a = *(const double2*)&rp0[k];
        double2 p0b = *(const double2*)&rp0[k + 2];
        double2 p1a = *(const double2*)&rp1[k];
        double2 p1b = *(const double2*)&rp1[k + 2];
        const float4 wv = wv4[(k >> 2) * 64 + o];
        const double wa = (double)wv.x, wb = (double)wv.y;
        const double wc = (double)wv.z, wd = (double)wv.w;
        a00 = fma(p0a.x, wa, a00);
        a01 = fma(p0a.y, wb, a01);
        a00 = fma(p0b.x, wc, a00);
        a01 = fma(p0b.y, wd, a01);
        a10 = fma(p1a.x, wa, a10);
        a11 = fma(p1a.y, wb, a11);
        a10 = fma(p1b.x, wc, a10);
        a11 = fma(p1b.y, wd, a11);
    }
    const double b1v = (double)fc1b[o];
    Hs[s2][o]     = fmax((a00 + a01) + b1v, 0.0);
    Hs[s2 + 1][o] = fmax((a10 + a11) + b1v, 0.0);
    __syncthreads();

    if (t < 32) {
        const int r = t >> 2, kc = t & 3;
        double sv = (double)fc2b[kc];
#pragma unroll 8
        for (int c = 0; c < 64; ++c) sv = fma(Hs[r][c], w2t[c * 4 + kc], sv);
        proj[(size_t)(row0 + r) * 4 + kc] = sv;
        double ssum = sv, sq = sv * sv;
        ssum += __shfl_xor(ssum, 4);   sq += __shfl_xor(sq, 4);
        ssum += __shfl_xor(ssum, 8);   sq += __shfl_xor(sq, 8);
        ssum += __shfl_xor(ssum, 16);  sq += __shfl_xor(sq, 16);
        if (t < 4) {
            psum[(size_t)blockIdx.x * 8 + t] = ssum;
            psum[(size_t)blockIdx.x * 8 + 4 + t] = sq;
        }
    }
}

// ---------------------------------------------------------------------------
// Kernel 3: stats-reduce (replicated, deterministic) + BatchNorm + row
// L2-normalize, f64. Emits pb32/pn32 + pn64. Unchanged from r8.
// ---------------------------------------------------------------------------
__global__ __launch_bounds__(256) void bn_kernel(
    const double* __restrict__ proj, const double* __restrict__ psum,
    const float* __restrict__ gamma, const float* __restrict__ beta,
    float* __restrict__ pb32, float* __restrict__ pn32,
    double* __restrict__ pn64) {

    __shared__ double red[256];
    __shared__ double stats_s[8];
    const int t = threadIdx.x;
    {
        const int c = t & 7, i0 = t >> 3;
        double v = 0.0;
        for (int i = i0; i < FC_NBLK; i += 32) v += psum[(size_t)i * 8 + c];
        red[t] = v;
    }
    __syncthreads();
    if (t < 8) {
        double sacc = 0.0;
        for (int j = 0; j < 32; ++j) sacc += red[t + 8 * j];
        stats_s[t] = sacc;
    }
    __syncthreads();

    const int i = blockIdx.x * 256 + t;
    double2 p01 = ((const double2*)proj)[2 * i];
    double2 p23 = ((const double2*)proj)[2 * i + 1];
    double pv[4] = {p01.x, p01.y, p23.x, p23.y};
    double o[4];
#pragma unroll
    for (int k = 0; k < 4; ++k) {
        double mean = stats_s[k] * (1.0 / 8192.0);
        double var  = stats_s[4 + k] * (1.0 / 8192.0) - mean * mean;
        double inv  = 1.0 / sqrt(var + 1e-5);
        o[k] = (pv[k] - mean) * inv * (double)gamma[k] + (double)beta[k];
    }
    double nrm = sqrt(o[0] * o[0] + o[1] * o[1] + o[2] * o[2] + o[3] * o[3]);
    double innv = 1.0 / (nrm + 1e-12);
    ((float4*)pb32)[i] = make_float4((float)o[0], (float)o[1], (float)o[2], (float)o[3]);
    double n0 = o[0] * innv, n1 = o[1] * innv, n2 = o[2] * innv, n3 = o[3] * innv;
    ((float4*)pn32)[i] = make_float4((float)n0, (float)n1, (float)n2, (float)n3);
    double2* pd = (double2*)(pn64 + (size_t)i * 4);
    pd[0] = make_double2(n0, n1);
    pd[1] = make_double2(n2, n3);
}

// ---------------------------------------------------------------------------
// Kernel 4: O(B^2) adjacency, j-SPLIT: 512 blocks (2/CU, 2 waves/SIMD for
// latency hiding). Block (rb,jh) does rows rb*32..+32 over j in
// [jh*4096, jh*4096+4096). Partials -> wpp[jh*8192 + row] (reuses proj mem).
// Diagonal included (fid(i,i)=1); removed in final_kernel.
// ---------------------------------------------------------------------------
#define CHUNK 1024
__global__ __launch_bounds__(256) void adj_kernel(
    const float* __restrict__ pn32, const float* __restrict__ pb32,
    const double* __restrict__ pn64, float* __restrict__ wpp) {

    __shared__ __align__(16) float4 pns[CHUNK];
    __shared__ __align__(16) float4 pbs[CHUNK];

    const int t = threadIdx.x;
    const int tg = t & 15, g = t >> 4;
    const int rb = blockIdx.x >> 1, jh = blockIdx.x & 1;
    const int rowb = rb * 32 + g * 2;
    const int jb0 = jh * 4096;

    float4 pni[2];
#pragma unroll
    for (int r = 0; r < 2; ++r) pni[r] = ((const float4*)pn32)[rowb + r];
    float w[2][4] = {};

    for (int base = jb0; base < jb0 + 4096; base += CHUNK) {
        for (int i = t; i < CHUNK; i += 256) {
            pns[i] = ((const float4*)pn32)[base + i];
            pbs[i] = ((const float4*)pb32)[base + i];
        }
        __syncthreads();
        for (int jj = 0; jj < CHUNK / 16; ++jj) {
            const int jl = jj * 16 + tg;
            float4 q = pns[jl];
            float4 pj = pbs[jl];
#pragma unroll
            for (int r = 0; r < 2; ++r) {
                float d = fmaf(pni[r].x, q.x, fmaf(pni[r].y, q.y,
                          fmaf(pni[r].z, q.z, pni[r].w * q.w)));
                float fid = d * d;
                float tdiff = fid - 0.9f;
                bool ok;
                if (fabsf(tdiff) < 2e-4f) {   // rare: exact recheck
                    const int j = base + jl;
                    const double2* pr = (const double2*)(pn64 + (size_t)(rowb + r) * 4);
                    const double2* pq = (const double2*)(pn64 + (size_t)j * 4);
                    double2 r0 = pr[0], r1 = pr[1], q0 = pq[0], q1 = pq[1];
                    double dd = fma(r0.x, q0.x, fma(r0.y, q0.y,
                                fma(r1.x, q1.x, r1.y * q1.y)));
                    ok = (dd * dd >= 0.9);
                } else {
                    ok = (tdiff >= 0.f);
                }
                float m = ok ? 1.f : 0.f;
                w[r][0] = fmaf(m, pj.x, w[r][0]);
                w[r][1] = fmaf(m, pj.y, w[r][1]);
                w[r][2] = fmaf(m, pj.z, w[r][2]);
                w[r][3] = fmaf(m, pj.w, w[r][3]);
            }
        }
        __syncthreads();
    }
#pragma unroll
    for (int msk = 1; msk < 16; msk <<= 1)
#pragma unroll
        for (int r = 0; r < 2; ++r) {
            w[r][0] += __shfl_xor(w[r][0], msk);
            w[r][1] += __shfl_xor(w[r][1], msk);
            w[r][2] += __shfl_xor(w[r][2], msk);
            w[r][3] += __shfl_xor(w[r][3], msk);
        }
    if (tg == 0) {
#pragma unroll
        for (int r = 0; r < 2; ++r)
            ((float4*)wpp)[jh * 8192 + rowb + r] =
                make_float4(w[r][0], w[r][1], w[r][2], w[r][3]);
    }
}

// ---------------------------------------------------------------------------
// Kernel 5: single-block epilogue. Combines j-half partials, removes
// diagonal, reduces sd in-block (f64), computes probs. 1024 threads.
// ---------------------------------------------------------------------------
__global__ __launch_bounds__(1024) void final_kernel(
    const float* __restrict__ pb32, const float* __restrict__ wpp,
    float* __restrict__ out) {

    __shared__ double lbase[8192];   // 64 KB
    __shared__ double wsum[16];
    __shared__ double kv_s;

    const int t = threadIdx.x;
    double sdl = 0.0;
    for (int r = t; r < 8192; r += 1024) {
        float4 a  = ((const float4*)wpp)[r];
        float4 bq = ((const float4*)wpp)[8192 + r];
        float4 p  = ((const float4*)pb32)[r];
        float w0 = a.x + bq.x - p.x;   // remove diagonal
        float w1 = a.y + bq.y - p.y;
        float w2 = a.z + bq.z - p.z;
        float w3 = a.w + bq.w - p.w;
        double lb = (double)p.x + p.y + p.z + p.w;
        lb = lb + w0 + w1 + w2 + w3;
        lbase[r] = lb;
        float d0 = p.x - w0, d1 = p.y - w1, d2 = p.z - w2, d3 = p.w - w3;
        sdl += (double)(d0 * d0 + d1 * d1 + d2 * d2 + d3 * d3);
    }
#pragma unroll
    for (int m = 1; m < 64; m <<= 1) sdl += __shfl_xor(sdl, m);
    if ((t & 63) == 0) wsum[t >> 6] = sdl;
    __syncthreads();
    if (t == 0) {
        double s = 0.0;
        for (int i = 0; i < 16; ++i) s += wsum[i];
        kv_s = exp(-s);
    }
    __syncthreads();
    const double kv = kv_s;
    for (int r = t; r < 8192; r += 1024) {
        double logit = lbase[r] + kv;
        double pr = 1.0 / (1.0 + exp(-logit));
        *(float2*)&out[2 * r] = make_float2((float)pr, (float)(1.0 - pr));
    }
}

// ---------------------------------------------------------------------------
extern "C" void kernel_launch(void* const* d_in, const int* in_sizes, int n_in,
                              void* d_out, int out_size, void* d_ws, size_t ws_size,
                              hipStream_t stream) {
    const float* x     = (const float*)d_in[0];
    const float* c1w   = (const float*)d_in[1];
    const float* c1b   = (const float*)d_in[2];
    const float* c2w   = (const float*)d_in[3];
    const float* c2b   = (const float*)d_in[4];
    const float* fc1w  = (const float*)d_in[5];
    const float* fc1b  = (const float*)d_in[6];
    const float* fc2w  = (const float*)d_in[7];
    const float* fc2b  = (const float*)d_in[8];
    const float* gamma = (const float*)d_in[9];
    const float* beta  = (const float*)d_in[10];
    float* out = (float*)d_out;

    char* ws = (char*)d_ws;
    double* proj  = (double*)(ws + OFF_PROJ);
    float*  wpp   = (float*)(ws + OFF_WPP);    // reuses proj region after bn
    double* pn64  = (double*)(ws + OFF_PN64);
    float*  pb32  = (float*)(ws + OFF_PB32);
    float*  pn32  = (float*)(ws + OFF_PN32);
    float*  w1t   = (float*)(ws + OFF_W1T);
    double* psum  = (double*)(ws + OFF_PSUM);
    void*   flat  = (void*)(ws + OFF_FLAT);

    // deterministic per-deployment branch (ws_size constant across calls)
    const bool f64flat = ws_size >= (size_t)OFF_FLAT + FLAT64_BYTES;

    if (f64flat) {
        conv_fused<true><<<B_IMG, 256, 0, stream>>>(x, c1w, c1b, c2w, c2b, fc1w, w1t, flat);
        fc_kernel<true><<<FC_NBLK, 256, 0, stream>>>(flat, w1t, fc1b, fc2w, fc2b, proj, psum);
    } else {
        conv_fused<false><<<B_IMG, 256, 0, stream>>>(x, c1w, c1b, c2w, c2b, fc1w, w1t, flat);
        fc_kernel<false><<<FC_NBLK, 256, 0, stream>>>(flat, w1t, fc1b, fc2w, fc2b, proj, psum);
    }
    bn_kernel<<<B_IMG / 256, 256, 0, stream>>>(proj, psum, gamma, beta, pb32, pn32, pn64);
    adj_kernel<<<512, 256, 0, stream>>>(pn32, pb32, pn64, wpp);
    final_kernel<<<1, 1024, 0, stream>>>(pb32, wpp, out);
}